// Round 9
// baseline (303.803 us; speedup 1.0000x reference)
//
#include <hip/hip_runtime.h>
#include <hip/hip_bf16.h>
#include <cstdint>

typedef unsigned short u16;
typedef unsigned int u32;
typedef __attribute__((ext_vector_type(4))) float f32x4;
typedef __attribute__((ext_vector_type(16))) float f32x16;
typedef __attribute__((ext_vector_type(8))) __bf16 bf16x8;

#define NH 16
#define NKV 4
#define SEQ 2048
#define NTOK 4096

__device__ inline u16 f2bf(float f) {
  return __builtin_bit_cast(u16, __float2bfloat16(f));
}
__device__ inline float bf2f(u16 u) {
  return __bfloat162float(__builtin_bit_cast(__hip_bfloat16, u));
}
__device__ inline u32 pk2(float a, float b) {
  return (u32)f2bf(a) | ((u32)f2bf(b) << 16);
}

#define GLDS(gp, lp) __builtin_amdgcn_global_load_lds( \
    (__attribute__((address_space(1))) void*)(gp), \
    (__attribute__((address_space(3))) void*)(lp), 16, 0, 0)

#define VMCNT0 asm volatile("s_waitcnt vmcnt(0)" ::: "memory")

// ---------------- RMSNorm (f32 in, bf16 out) ----------------
__global__ __launch_bounds__(256) void rmsnorm_kernel(
    const float* __restrict__ x, const float* __restrict__ w,
    u16* __restrict__ out) {
  int row = blockIdx.x;
  int tid = threadIdx.x;
  const float4 v = reinterpret_cast<const float4*>(x + (size_t)row * 1024)[tid];
  float ss = v.x * v.x + v.y * v.y + v.z * v.z + v.w * v.w;
#pragma unroll
  for (int off = 32; off; off >>= 1) ss += __shfl_xor(ss, off);
  __shared__ float red[4];
  int lane = tid & 63, wid = tid >> 6;
  if (lane == 0) red[wid] = ss;
  __syncthreads();
  float tot = red[0] + red[1] + red[2] + red[3];
  float r = rsqrtf(tot * (1.0f / 1024.0f) + 1e-6f);
  const float4 wv = reinterpret_cast<const float4*>(w)[tid];
  ushort4 o;
  o.x = f2bf(v.x * r * wv.x);
  o.y = f2bf(v.y * r * wv.y);
  o.z = f2bf(v.z * r * wv.z);
  o.w = f2bf(v.w * r * wv.w);
  reinterpret_cast<ushort4*>(out + (size_t)row * 1024)[tid] = o;
}

// ---------------- weight transpose + cast: src[K][N] f32 -> dst[N][K] bf16 ----------------
__global__ __launch_bounds__(256) void transpose_cast_kernel(
    const float* __restrict__ src, u16* __restrict__ dst, int K, int N) {
  __shared__ float tile[32][33];
  int n0 = blockIdx.x * 32, k0 = blockIdx.y * 32;
  int tx = threadIdx.x & 31, ty = threadIdx.x >> 5;  // ty: 0..7
#pragma unroll
  for (int i = 0; i < 4; i++)
    tile[ty + i * 8][tx] = src[(size_t)(k0 + ty + i * 8) * N + n0 + tx];
  __syncthreads();
#pragma unroll
  for (int i = 0; i < 4; i++)
    dst[(size_t)(n0 + ty + i * 8) * K + k0 + tx] = f2bf(tile[tx][ty + i * 8]);
}

// Shared epilogue
template <int EP>
__device__ inline void epi_store(float v, size_t idx, int col,
                                 float* __restrict__ outf,
                                 const float* __restrict__ res,
                                 const float* __restrict__ scale,
                                 u16* __restrict__ outb) {
  if (EP == 0) {
    outf[idx] = v;
  } else if (EP == 1) {
    outf[idx] = res[idx] + v * scale[col];
  } else if (EP == 2) {
    outb[idx] = f2bf(v / (1.0f + __expf(-v)));
  } else {
    outb[idx] = f2bf(bf2f(outb[idx]) * v);
  }
}

// ---------------- gemmA: 256x256 tile, BK=64, 8 waves, 1 barrier/tile ----------------
template <int EP>
__global__ __launch_bounds__(512, 1) void gemmA(
    const u16* __restrict__ A, const u16* __restrict__ Bt,
    int M, int N, int K,
    float* __restrict__ outf, const float* __restrict__ res,
    const float* __restrict__ scale, u16* __restrict__ outb) {
  __shared__ u16 SA[2][256 * 64];
  __shared__ u16 SB[2][256 * 64];
  const int tid = threadIdx.x, lane = tid & 63, w = tid >> 6;
  const int wr = w >> 2, wc = w & 3;
  const int lg = lane >> 4, lc = lane & 15, cx = lc & 7;

  const int nbn = N >> 8;  // 16 for gate/up
  const int r8 = blockIdx.x & 7, j = blockIdx.x >> 3;
  const int bm = (((r8 >> 1) << 2) + (j & 3)) << 8;
  const int bn = ((r8 & 1) * (nbn >> 1) + (j >> 2)) << 8;

  const int swrow = lane >> 3;                 // 0..7
  const int swcol = (lane & 7) ^ swrow;        // pre-swizzled source chunk
  const u16* gA = A + (size_t)(bm + w * 16 + swrow) * K + swcol * 8;
  const u16* gB = Bt + (size_t)(bn + w * 16 + swrow) * K + swcol * 8;

  const int NT = K >> 6;
  f32x4 acc[8][4] = {};

#define SGA(T_) do { int sl_ = (T_) & 1; size_t ko_ = (size_t)(T_) * 64; \
    GLDS(gA + ko_,                    &SA[sl_][(w * 16) * 64]); \
    GLDS(gA + ko_ + (size_t)8 * K,    &SA[sl_][(w * 16 + 8) * 64]); \
    GLDS(gA + ko_ + (size_t)128 * K,  &SA[sl_][(128 + w * 16) * 64]); \
    GLDS(gA + ko_ + (size_t)136 * K,  &SA[sl_][(136 + w * 16) * 64]); } while (0)
#define SGB(T_) do { int sl_ = (T_) & 1; size_t ko_ = (size_t)(T_) * 64; \
    GLDS(gB + ko_,                    &SB[sl_][(w * 16) * 64]); \
    GLDS(gB + ko_ + (size_t)8 * K,    &SB[sl_][(w * 16 + 8) * 64]); \
    GLDS(gB + ko_ + (size_t)128 * K,  &SB[sl_][(128 + w * 16) * 64]); \
    GLDS(gB + ko_ + (size_t)136 * K,  &SB[sl_][(136 + w * 16) * 64]); } while (0)

  SGA(0);
  SGB(0);
  VMCNT0;
  __builtin_amdgcn_s_barrier();

  for (int t = 0; t < NT; ++t) {
    const u16* sa = &SA[t & 1][0];
    const u16* sb = &SB[t & 1][0];
    const bool more = (t + 1 < NT);

    bf16x8 bfr[4][2];
#pragma unroll
    for (int n = 0; n < 4; n++) {
      const int row = wc * 64 + n * 16 + lc;
#pragma unroll
      for (int ks = 0; ks < 2; ks++)
        bfr[n][ks] = *reinterpret_cast<const bf16x8*>(
            &sb[row * 64 + ((((ks << 2) | lg) ^ cx) << 3)]);
    }
    bf16x8 afr[4][2];
#pragma unroll
    for (int i = 0; i < 4; i++) {
      const int row = wr * 128 + i * 16 + lc;
#pragma unroll
      for (int ks = 0; ks < 2; ks++)
        afr[i][ks] = *reinterpret_cast<const bf16x8*>(
            &sa[row * 64 + ((((ks << 2) | lg) ^ cx) << 3)]);
    }
    if (more) SGA(t + 1);
    __builtin_amdgcn_s_setprio(1);
#pragma unroll
    for (int i = 0; i < 4; i++)
#pragma unroll
      for (int n = 0; n < 4; n++) {
        acc[i][n] = __builtin_amdgcn_mfma_f32_16x16x32_bf16(afr[i][0], bfr[n][0], acc[i][n], 0, 0, 0);
        acc[i][n] = __builtin_amdgcn_mfma_f32_16x16x32_bf16(afr[i][1], bfr[n][1], acc[i][n], 0, 0, 0);
      }
    __builtin_amdgcn_s_setprio(0);
#pragma unroll
    for (int i = 0; i < 4; i++) {
      const int row = wr * 128 + 64 + i * 16 + lc;
#pragma unroll
      for (int ks = 0; ks < 2; ks++)
        afr[i][ks] = *reinterpret_cast<const bf16x8*>(
            &sa[row * 64 + ((((ks << 2) | lg) ^ cx) << 3)]);
    }
    if (more) SGB(t + 1);
    __builtin_amdgcn_s_setprio(1);
#pragma unroll
    for (int i = 0; i < 4; i++)
#pragma unroll
      for (int n = 0; n < 4; n++) {
        acc[4 + i][n] = __builtin_amdgcn_mfma_f32_16x16x32_bf16(afr[i][0], bfr[n][0], acc[4 + i][n], 0, 0, 0);
        acc[4 + i][n] = __builtin_amdgcn_mfma_f32_16x16x32_bf16(afr[i][1], bfr[n][1], acc[4 + i][n], 0, 0, 0);
      }
    __builtin_amdgcn_s_setprio(0);
    VMCNT0;
    __builtin_amdgcn_s_barrier();
  }
#undef SGA
#undef SGB

#pragma unroll
  for (int mi = 0; mi < 8; mi++)
#pragma unroll
    for (int ni = 0; ni < 4; ni++)
#pragma unroll
      for (int rg = 0; rg < 4; rg++) {
        const int row = bm + wr * 128 + mi * 16 + lg * 4 + rg;
        const int col = bn + wc * 64 + ni * 16 + lc;
        epi_store<EP>(acc[mi][ni][rg], (size_t)row * N + col, col, outf, res, scale, outb);
      }
}

// ---------------- gemmB: 128x128 tile, BK=64, 4 waves ----------------
template <int EP>
__global__ __launch_bounds__(256, 1) void gemmB(
    const u16* __restrict__ A, const u16* __restrict__ Bt,
    int M, int N, int K,
    float* __restrict__ outf, const float* __restrict__ res,
    const float* __restrict__ scale, u16* __restrict__ outb) {
  __shared__ u16 SA[2][128 * 64];
  __shared__ u16 SB[2][128 * 64];
  const int tid = threadIdx.x, lane = tid & 63, w = tid >> 6;  // 0..3
  const int wr = w >> 1, wc = w & 1;
  const int lg = lane >> 4, lc = lane & 15, cx = lc & 7;

  const int r8 = blockIdx.x & 7, j = blockIdx.x >> 3;
  const int bm = ((r8 << 2) + (j & 3)) << 7;   // M=4096: 32 m-blocks, 4 per XCD
  const int bn = (j >> 2) << 7;

  const int swrow = lane >> 3;
  const int swcol = (lane & 7) ^ swrow;
  const u16* gA = A + (size_t)(bm + w * 32 + swrow) * K + swcol * 8;
  const u16* gB = Bt + (size_t)(bn + w * 32 + swrow) * K + swcol * 8;

  const int NT = K >> 6;
  f32x4 acc[4][4] = {};

#define SG2(T_) do { int sl_ = (T_) & 1; size_t ko_ = (size_t)(T_) * 64; \
    GLDS(gA + ko_,                   &SA[sl_][(w * 32) * 64]); \
    GLDS(gA + ko_ + (size_t)8 * K,   &SA[sl_][(w * 32 + 8) * 64]); \
    GLDS(gA + ko_ + (size_t)16 * K,  &SA[sl_][(w * 32 + 16) * 64]); \
    GLDS(gA + ko_ + (size_t)24 * K,  &SA[sl_][(w * 32 + 24) * 64]); \
    GLDS(gB + ko_,                   &SB[sl_][(w * 32) * 64]); \
    GLDS(gB + ko_ + (size_t)8 * K,   &SB[sl_][(w * 32 + 8) * 64]); \
    GLDS(gB + ko_ + (size_t)16 * K,  &SB[sl_][(w * 32 + 16) * 64]); \
    GLDS(gB + ko_ + (size_t)24 * K,  &SB[sl_][(w * 32 + 24) * 64]); } while (0)

  SG2(0);
  VMCNT0;
  __builtin_amdgcn_s_barrier();

  for (int t = 0; t < NT; ++t) {
    const u16* sa = &SA[t & 1][0];
    const u16* sb = &SB[t & 1][0];
    const bool more = (t + 1 < NT);

    bf16x8 bfr[4][2], afr[4][2];
#pragma unroll
    for (int n = 0; n < 4; n++) {
      const int row = wc * 64 + n * 16 + lc;
#pragma unroll
      for (int ks = 0; ks < 2; ks++)
        bfr[n][ks] = *reinterpret_cast<const bf16x8*>(
            &sb[row * 64 + ((((ks << 2) | lg) ^ cx) << 3)]);
    }
#pragma unroll
    for (int i = 0; i < 4; i++) {
      const int row = wr * 64 + i * 16 + lc;
#pragma unroll
      for (int ks = 0; ks < 2; ks++)
        afr[i][ks] = *reinterpret_cast<const bf16x8*>(
            &sa[row * 64 + ((((ks << 2) | lg) ^ cx) << 3)]);
    }
    if (more) SG2(t + 1);
    __builtin_amdgcn_s_setprio(1);
#pragma unroll
    for (int i = 0; i < 4; i++)
#pragma unroll
      for (int n = 0; n < 4; n++) {
        acc[i][n] = __builtin_amdgcn_mfma_f32_16x16x32_bf16(afr[i][0], bfr[n][0], acc[i][n], 0, 0, 0);
        acc[i][n] = __builtin_amdgcn_mfma_f32_16x16x32_bf16(afr[i][1], bfr[n][1], acc[i][n], 0, 0, 0);
      }
    __builtin_amdgcn_s_setprio(0);
    VMCNT0;
    __builtin_amdgcn_s_barrier();
  }
#undef SG2

#pragma unroll
  for (int mi = 0; mi < 4; mi++)
#pragma unroll
    for (int ni = 0; ni < 4; ni++)
#pragma unroll
      for (int rg = 0; rg < 4; rg++) {
        const int row = bm + wr * 64 + mi * 16 + lg * 4 + rg;
        const int col = bn + wc * 64 + ni * 16 + lc;
        epi_store<EP>(acc[mi][ni][rg], (size_t)row * N + col, col, outf, res, scale, outb);
      }
}

// ---------------- RoPE: qkv f32 -> q_rope (pre-scaled by 0.125*log2e) bf16, k_rope bf16 ----------------
__global__ __launch_bounds__(256) void rope_kernel(
    const float* __restrict__ qkv, const float* __restrict__ cosb,
    const float* __restrict__ sinb, u16* __restrict__ qr, u16* __restrict__ kr) {
  int idx = blockIdx.x * 256 + threadIdx.x;  // B*S*20*32 total
  int d = idx & 31;
  int t = idx >> 5;
  int head = t % 20;
  int bs = t / 20;  // 0..4095
  int s = bs & (SEQ - 1);
  int b = bs >> 11;
  const float* row = qkv + (size_t)bs * 1536;
  float c = cosb[s * 32 + d], sn = sinb[s * 32 + d];
  const float QSC = 0.18033688011112042f;  // 0.125 * log2(e)
  float x1, x2;
  if (head < 16) {
    x1 = row[head * 64 + d];
    x2 = row[head * 64 + d + 32];
    size_t o = ((size_t)(b * NH + head) * SEQ + s) * 64 + d;
    qr[o] = f2bf((x1 * c + x2 * sn) * QSC);
    qr[o + 32] = f2bf((x2 * c - x1 * sn) * QSC);
  } else {
    int kh = head - 16;
    x1 = row[1024 + kh * 64 + d];
    x2 = row[1024 + kh * 64 + d + 32];
    size_t o = ((size_t)(b * NKV + kh) * SEQ + s) * 64 + d;
    kr[o] = f2bf(x1 * c + x2 * sn);
    kr[o + 32] = f2bf(x2 * c - x1 * sn);
  }
}

// ---------------- V transpose: qkv f32 -> vt [b][kv][d][s] bf16 ----------------
__global__ __launch_bounds__(256) void vtrans_kernel(
    const float* __restrict__ qkv, u16* __restrict__ vt) {
  int blk = blockIdx.x;
  int st = blk & 31; blk >>= 5;
  int kvh = blk & 3; blk >>= 2;
  int b = blk;
  __shared__ u16 tile[64][65];
  int tx = threadIdx.x & 63;
  int ty = threadIdx.x >> 6;  // 0..3
  int s0 = st * 64;
#pragma unroll
  for (int i = 0; i < 16; i++) {
    int sl = i * 4 + ty;
    tile[sl][tx] = f2bf(qkv[(size_t)(b * SEQ + s0 + sl) * 1536 + 1280 + kvh * 64 + tx]);
  }
  __syncthreads();
  size_t vbase = (size_t)(b * NKV + kvh) * 64 * SEQ;
#pragma unroll
  for (int i = 0; i < 16; i++) {
    int dd = i * 4 + ty;
    vt[vbase + (size_t)dd * SEQ + s0 + tx] = tile[tx][dd];
  }
}

// ---------------- Flash attention v6: 256-row super-strip, 8 co-active waves ----------------
// Block = (b, h, 256-row q range); wave w owns rows q0 = 256i + 32w .. +31.
// All waves active within +-3 tiles of each other -> 2 computing waves/SIMD.
__global__ __launch_bounds__(512, 1) void attn_kernel(
    const u16* __restrict__ qr, const u16* __restrict__ kr,
    const u16* __restrict__ vt, u16* __restrict__ out) {
  __shared__ u16 Ks[2][64 * 64];   // [key][d], XOR-swizzled
  __shared__ u16 Vs[2][64 * 64];   // [d][key], XOR-swizzled

  const int n = blockIdx.x;                 // 256 blocks
  const int g = n & 7;                      // b*4+kvh -> XCD-aligned
  const int b = g >> 2, kvh = g & 3;
  const int h = kvh * 4 + ((n >> 3) & 3);
  const int i = n >> 5;                     // super-strip 0..7

  const int tid = threadIdx.x;
  const int lane = tid & 63, w = tid >> 6;  // 8 waves
  const int l31 = lane & 31, hi = lane >> 5;

  const int q0w = i * 256 + w * 32;         // this wave's 32 q rows
  const int qg = q0w + l31;
  const int nt = 4 * i + 4;                 // tiles for the top wave

  // Q fragments (B-operand, 32x32x16): qf[c][e] = Q[qg][16c + 8hi + e]
  bf16x8 qf[4];
  {
    const u16* qp = qr + ((size_t)(b * NH + h) * SEQ + qg) * 64 + 8 * hi;
#pragma unroll
    for (int c = 0; c < 4; c++)
      qf[c] = *reinterpret_cast<const bf16x8*>(qp + 16 * c);
  }
  VMCNT0;  // drain Q loads so in-loop vmcnt counting sees only GLDS

  // staging: wave stages 8 K rows + 8 V d-rows, pre-swizzled source
  const int srow = lane >> 3;                      // 0..7
  const int scw = ((lane & 7) ^ srow) << 3;        // pre-swizzled col (u16)
  const u16* ksrc = kr + (size_t)(b * NKV + kvh) * SEQ * 64 + (size_t)(w * 8 + srow) * 64 + scw;
  const u16* vsrc = vt + ((size_t)(b * NKV + kvh) * 64 + w * 8 + srow) * SEQ + scw;

#define STAGEA(bufi, t) do { \
    GLDS(ksrc + (size_t)(t) * 64 * 64, &Ks[bufi][(w * 8) * 64]); \
    GLDS(vsrc + (size_t)(t) * 64,      &Vs[bufi][(w * 8) * 64]); \
  } while (0)

  STAGEA(0, 0);

  float mm = -1e30f, ll = 0.0f;
  f32x16 oacc[2] = {};  // [dch]: q = (r&3)+8*(r>>2)+4*hi + q0w, d = dch*32 + l31

  int buf = 0;
  for (int t = 0; t < nt; ++t) {
    if (t + 1 < nt) {
      STAGEA(buf ^ 1, t + 1);
      asm volatile("s_waitcnt vmcnt(2)" ::: "memory");
    } else {
      VMCNT0;
    }
    __builtin_amdgcn_s_barrier();
    __builtin_amdgcn_sched_barrier(0);

    const int c0 = t * 64;
    if (c0 <= q0w + 31) {
      // QK^T swapped: sc[a] = S^T over keys [c0+32a, c0+32a+32), q cols
      f32x16 sc[2] = {};
      __builtin_amdgcn_s_setprio(1);
#pragma unroll
      for (int a = 0; a < 2; a++) {
        const int row = a * 32 + l31;
#pragma unroll
        for (int c = 0; c < 4; c++) {
          bf16x8 kf = *reinterpret_cast<const bf16x8*>(
              &Ks[buf][row * 64 + (((2 * c + hi) ^ (row & 7)) << 3)]);
          sc[a] = __builtin_amdgcn_mfma_f32_32x32x16_bf16(kf, qf[c], sc[a], 0, 0, 0);
        }
      }
      __builtin_amdgcn_s_setprio(0);

      // V fragments (B-operand): vf[dch][c][e] = V[key=16c+8hi+e][d=dch*32+l31]
      bf16x8 vf[2][4];
#pragma unroll
      for (int dch = 0; dch < 2; dch++) {
        const int row = dch * 32 + l31;
#pragma unroll
        for (int c = 0; c < 4; c++)
          vf[dch][c] = *reinterpret_cast<const bf16x8*>(
              &Vs[buf][row * 64 + (((2 * c + hi) ^ (row & 7)) << 3)]);
      }

      // causal mask (boundary tiles only)
      if (c0 + 63 > q0w) {
#pragma unroll
        for (int a = 0; a < 2; a++)
#pragma unroll
          for (int r = 0; r < 16; r++) {
            const int key = c0 + 32 * a + (r & 3) + 8 * (r >> 2) + 4 * hi;
            if (key > qg) sc[a][r] = -1e30f;
          }
      }

      // in-lane max + one cross-half exchange
      float mx = -1e30f;
#pragma unroll
      for (int a = 0; a < 2; a++)
#pragma unroll
        for (int r = 0; r < 16; r++) mx = fmaxf(mx, sc[a][r]);
      mx = fmaxf(mx, __shfl_xor(mx, 32));

      // defer-max rescale (rare)
      if (!__all(mx - mm <= 11.5f)) {
        float mn = fmaxf(mm, mx);
        float al = exp2f(mm - mn);
        mm = mn;
        ll *= al;
#pragma unroll
        for (int r = 0; r < 16; r++) {
          float arr = __shfl(al, (r & 3) + 8 * (r >> 2) + 4 * hi);
          oacc[0][r] *= arr;
          oacc[1][r] *= arr;
        }
      }

      // exp2 + in-lane sum + one cross-half exchange
      float rs = 0.0f;
#pragma unroll
      for (int a = 0; a < 2; a++)
#pragma unroll
        for (int r = 0; r < 16; r++) {
          float p = exp2f(sc[a][r] - mm);
          sc[a][r] = p;
          rs += p;
        }
      rs += __shfl_xor(rs, 32);
      ll += rs;

      // P -> bf16 A-fragments in-register (half exchange)
      bf16x8 pa[4];
#pragma unroll
      for (int c = 0; c < 4; c++) {
        const int a = c >> 1;
        const int bb = 8 * (c & 1);
        u32 A0 = pk2(sc[a][bb + 0], sc[a][bb + 1]);
        u32 A1 = pk2(sc[a][bb + 2], sc[a][bb + 3]);
        u32 B0 = pk2(sc[a][bb + 4], sc[a][bb + 5]);
        u32 B1 = pk2(sc[a][bb + 6], sc[a][bb + 7]);
        u32 s0 = hi ? A0 : B0;
        u32 s1 = hi ? A1 : B1;
        u32 r0 = (u32)__shfl_xor((int)s0, 32);
        u32 r1 = (u32)__shfl_xor((int)s1, 32);
        u32 w0 = hi ? r0 : A0;
        u32 w1 = hi ? r1 : A1;
        u32 w2 = hi ? B0 : r0;
        u32 w3 = hi ? B1 : r1;
        uint4 pw;
        pw.x = w0; pw.y = w1; pw.z = w2; pw.w = w3;
        pa[c] = __builtin_bit_cast(bf16x8, pw);
      }

      // PV: oacc[dch] += P * V
      __builtin_amdgcn_s_setprio(1);
#pragma unroll
      for (int c = 0; c < 4; c++) {
        oacc[0] = __builtin_amdgcn_mfma_f32_32x32x16_bf16(pa[c], vf[0][c], oacc[0], 0, 0, 0);
        oacc[1] = __builtin_amdgcn_mfma_f32_32x32x16_bf16(pa[c], vf[1][c], oacc[1], 0, 0, 0);
      }
      __builtin_amdgcn_s_setprio(0);
    }
    asm volatile("s_waitcnt lgkmcnt(0)" ::: "memory");
    __builtin_amdgcn_s_barrier();
    __builtin_amdgcn_sched_barrier(0);
    buf ^= 1;
  }
#undef STAGEA

  const float li = 1.0f / ll;  // stats at q = q0w + l31
#pragma unroll
  for (int r = 0; r < 16; r++) {
    const int qloc = (r & 3) + 8 * (r >> 2) + 4 * hi;
    float liq = __shfl(li, qloc);
    const int q = q0w + qloc;
    u16* orow = out + (size_t)(b * SEQ + q) * 1024 + h * 64 + l31;
    orow[0] = f2bf(oacc[0][r] * liq);
    orow[32] = f2bf(oacc[1][r] * liq);
  }
}

extern "C" void kernel_launch(void* const* d_in, const int* in_sizes, int n_in,
                              void* d_out, int out_size, void* d_ws, size_t ws_size,
                              hipStream_t stream) {
  const float* x = (const float*)d_in[0];
  const float* w_norm1 = (const float*)d_in[1];
  const float* wq = (const float*)d_in[2];
  const float* wk = (const float*)d_in[3];
  const float* wv = (const float*)d_in[4];
  const float* wo = (const float*)d_in[5];
  const float* attn_scale = (const float*)d_in[6];
  const float* w_norm2 = (const float*)d_in[7];
  const float* wg = (const float*)d_in[8];
  const float* wu = (const float*)d_in[9];
  const float* wd = (const float*)d_in[10];
  const float* mlp_scale = (const float*)d_in[11];
  const float* cosb = (const float*)d_in[12];
  const float* sinb = (const float*)d_in[13];
  float* out = (float*)d_out;

  char* ws = (char*)d_ws;
  u16* wqkv_t = (u16*)(ws + 0);            // 1536x1024 bf16
  u16* wo_t = (u16*)(ws + 3145728);        // 1024x1024 bf16
  u16* wg_t = (u16*)(ws + 5242880);        // 4096x1024 bf16
  u16* wu_t = (u16*)(ws + 13631488);
  u16* wd_t = (u16*)(ws + 22020096);       // 1024x4096 bf16
  u16* xn = (u16*)(ws + 30408704);         // 4096x1024 bf16 (reused for xn2)
  float* qkv = (float*)(ws + 38797312);    // 4096x1536 f32
  u16* attn_o = (u16*)(ws + 38797312);     // alias (qkv dead)
  float* x1 = (float*)(ws + 47185920);     // 4096x1024 f32
  u16* q_rope = (u16*)(ws + 63963136);     // 2*16*2048*64 bf16
  u16* k_rope = (u16*)(ws + 72351744);     // 2*4*2048*64 bf16
  u16* vt = (u16*)(ws + 74448896);         // 2*4*64*2048 bf16
  u16* hbuf = (u16*)(ws + 63963136);       // alias (rope dead in FFN phase)

  dim3 tb(256);
  transpose_cast_kernel<<<dim3(32, 32), tb, 0, stream>>>(wq, wqkv_t, 1024, 1024);
  transpose_cast_kernel<<<dim3(8, 32), tb, 0, stream>>>(wk, wqkv_t + (size_t)1024 * 1024, 1024, 256);
  transpose_cast_kernel<<<dim3(8, 32), tb, 0, stream>>>(wv, wqkv_t + (size_t)1280 * 1024, 1024, 256);
  transpose_cast_kernel<<<dim3(32, 32), tb, 0, stream>>>(wo, wo_t, 1024, 1024);
  transpose_cast_kernel<<<dim3(128, 32), tb, 0, stream>>>(wg, wg_t, 1024, 4096);
  transpose_cast_kernel<<<dim3(128, 32), tb, 0, stream>>>(wu, wu_t, 1024, 4096);
  transpose_cast_kernel<<<dim3(32, 128), tb, 0, stream>>>(wd, wd_t, 4096, 1024);

  rmsnorm_kernel<<<4096, tb, 0, stream>>>(x, w_norm1, xn);
  gemmB<0><<<dim3(384), dim3(256), 0, stream>>>(xn, wqkv_t, 4096, 1536, 1024, qkv, nullptr, nullptr, nullptr);
  rope_kernel<<<10240, tb, 0, stream>>>(qkv, cosb, sinb, q_rope, k_rope);
  vtrans_kernel<<<2 * 4 * 32, tb, 0, stream>>>(qkv, vt);
  attn_kernel<<<256, dim3(512), 0, stream>>>(q_rope, k_rope, vt, attn_o);
  gemmB<1><<<dim3(256), dim3(256), 0, stream>>>(attn_o, wo_t, 4096, 1024, 1024, x1, x, attn_scale, nullptr);
  rmsnorm_kernel<<<4096, tb, 0, stream>>>(x1, w_norm2, xn);
  gemmA<2><<<dim3(256), dim3(512), 0, stream>>>(xn, wg_t, 4096, 4096, 1024, nullptr, nullptr, nullptr, hbuf);
  gemmA<3><<<dim3(256), dim3(512), 0, stream>>>(xn, wu_t, 4096, 4096, 1024, nullptr, nullptr, nullptr, hbuf);
  gemmB<1><<<dim3(256), dim3(256), 0, stream>>>(hbuf, wd_t, 4096, 1024, 4096, out, x1, mlp_scale, nullptr);
}

// Round 10
// 291.667 us; speedup vs baseline: 1.0416x; 1.0416x over previous
//
#include <hip/hip_runtime.h>
#include <hip/hip_bf16.h>
#include <cstdint>

typedef unsigned short u16;
typedef unsigned int u32;
typedef __attribute__((ext_vector_type(4))) float f32x4;
typedef __attribute__((ext_vector_type(16))) float f32x16;
typedef __attribute__((ext_vector_type(8))) __bf16 bf16x8;

#define NH 16
#define NKV 4
#define SEQ 2048
#define NTOK 4096

__device__ inline u16 f2bf(float f) {
  return __builtin_bit_cast(u16, __float2bfloat16(f));
}
__device__ inline float bf2f(u16 u) {
  return __bfloat162float(__builtin_bit_cast(__hip_bfloat16, u));
}
__device__ inline u32 pk2(float a, float b) {
  return (u32)f2bf(a) | ((u32)f2bf(b) << 16);
}

#define GLDS(gp, lp) __builtin_amdgcn_global_load_lds( \
    (__attribute__((address_space(1))) void*)(gp), \
    (__attribute__((address_space(3))) void*)(lp), 16, 0, 0)

#define VMCNT0 asm volatile("s_waitcnt vmcnt(0)" ::: "memory")

// ---------------- RMSNorm (f32 in, bf16 out) ----------------
__global__ __launch_bounds__(256) void rmsnorm_kernel(
    const float* __restrict__ x, const float* __restrict__ w,
    u16* __restrict__ out) {
  int row = blockIdx.x;
  int tid = threadIdx.x;
  const float4 v = reinterpret_cast<const float4*>(x + (size_t)row * 1024)[tid];
  float ss = v.x * v.x + v.y * v.y + v.z * v.z + v.w * v.w;
#pragma unroll
  for (int off = 32; off; off >>= 1) ss += __shfl_xor(ss, off);
  __shared__ float red[4];
  int lane = tid & 63, wid = tid >> 6;
  if (lane == 0) red[wid] = ss;
  __syncthreads();
  float tot = red[0] + red[1] + red[2] + red[3];
  float r = rsqrtf(tot * (1.0f / 1024.0f) + 1e-6f);
  const float4 wv = reinterpret_cast<const float4*>(w)[tid];
  ushort4 o;
  o.x = f2bf(v.x * r * wv.x);
  o.y = f2bf(v.y * r * wv.y);
  o.z = f2bf(v.z * r * wv.z);
  o.w = f2bf(v.w * r * wv.w);
  reinterpret_cast<ushort4*>(out + (size_t)row * 1024)[tid] = o;
}

// ---------------- weight transpose + cast: src[K][N] f32 -> dst[N][K] bf16 ----------------
__global__ __launch_bounds__(256) void transpose_cast_kernel(
    const float* __restrict__ src, u16* __restrict__ dst, int K, int N) {
  __shared__ float tile[32][33];
  int n0 = blockIdx.x * 32, k0 = blockIdx.y * 32;
  int tx = threadIdx.x & 31, ty = threadIdx.x >> 5;  // ty: 0..7
#pragma unroll
  for (int i = 0; i < 4; i++)
    tile[ty + i * 8][tx] = src[(size_t)(k0 + ty + i * 8) * N + n0 + tx];
  __syncthreads();
#pragma unroll
  for (int i = 0; i < 4; i++)
    dst[(size_t)(n0 + ty + i * 8) * K + k0 + tx] = f2bf(tile[tx][ty + i * 8]);
}

// Shared epilogue
template <int EP>
__device__ inline void epi_store(float v, size_t idx, int col,
                                 float* __restrict__ outf,
                                 const float* __restrict__ res,
                                 const float* __restrict__ scale,
                                 u16* __restrict__ outb) {
  if (EP == 0) {
    outf[idx] = v;
  } else if (EP == 1) {
    outf[idx] = res[idx] + v * scale[col];
  } else if (EP == 2) {
    outb[idx] = f2bf(v / (1.0f + __expf(-v)));
  } else {
    outb[idx] = f2bf(bf2f(outb[idx]) * v);
  }
}

// ---------------- gemmA: 256x256 tile, BK=64, 8 waves, 1 barrier/tile ----------------
template <int EP>
__global__ __launch_bounds__(512, 1) void gemmA(
    const u16* __restrict__ A, const u16* __restrict__ Bt,
    int M, int N, int K,
    float* __restrict__ outf, const float* __restrict__ res,
    const float* __restrict__ scale, u16* __restrict__ outb) {
  __shared__ u16 SA[2][256 * 64];
  __shared__ u16 SB[2][256 * 64];
  const int tid = threadIdx.x, lane = tid & 63, w = tid >> 6;
  const int wr = w >> 2, wc = w & 3;
  const int lg = lane >> 4, lc = lane & 15, cx = lc & 7;

  const int nbn = N >> 8;  // 16 for gate/up
  const int r8 = blockIdx.x & 7, j = blockIdx.x >> 3;
  const int bm = (((r8 >> 1) << 2) + (j & 3)) << 8;
  const int bn = ((r8 & 1) * (nbn >> 1) + (j >> 2)) << 8;

  const int swrow = lane >> 3;                 // 0..7
  const int swcol = (lane & 7) ^ swrow;        // pre-swizzled source chunk
  const u16* gA = A + (size_t)(bm + w * 16 + swrow) * K + swcol * 8;
  const u16* gB = Bt + (size_t)(bn + w * 16 + swrow) * K + swcol * 8;

  const int NT = K >> 6;
  f32x4 acc[8][4] = {};

#define SGA(T_) do { int sl_ = (T_) & 1; size_t ko_ = (size_t)(T_) * 64; \
    GLDS(gA + ko_,                    &SA[sl_][(w * 16) * 64]); \
    GLDS(gA + ko_ + (size_t)8 * K,    &SA[sl_][(w * 16 + 8) * 64]); \
    GLDS(gA + ko_ + (size_t)128 * K,  &SA[sl_][(128 + w * 16) * 64]); \
    GLDS(gA + ko_ + (size_t)136 * K,  &SA[sl_][(136 + w * 16) * 64]); } while (0)
#define SGB(T_) do { int sl_ = (T_) & 1; size_t ko_ = (size_t)(T_) * 64; \
    GLDS(gB + ko_,                    &SB[sl_][(w * 16) * 64]); \
    GLDS(gB + ko_ + (size_t)8 * K,    &SB[sl_][(w * 16 + 8) * 64]); \
    GLDS(gB + ko_ + (size_t)128 * K,  &SB[sl_][(128 + w * 16) * 64]); \
    GLDS(gB + ko_ + (size_t)136 * K,  &SB[sl_][(136 + w * 16) * 64]); } while (0)

  SGA(0);
  SGB(0);
  VMCNT0;
  __builtin_amdgcn_s_barrier();

  for (int t = 0; t < NT; ++t) {
    const u16* sa = &SA[t & 1][0];
    const u16* sb = &SB[t & 1][0];
    const bool more = (t + 1 < NT);

    bf16x8 bfr[4][2];
#pragma unroll
    for (int n = 0; n < 4; n++) {
      const int row = wc * 64 + n * 16 + lc;
#pragma unroll
      for (int ks = 0; ks < 2; ks++)
        bfr[n][ks] = *reinterpret_cast<const bf16x8*>(
            &sb[row * 64 + ((((ks << 2) | lg) ^ cx) << 3)]);
    }
    bf16x8 afr[4][2];
#pragma unroll
    for (int i = 0; i < 4; i++) {
      const int row = wr * 128 + i * 16 + lc;
#pragma unroll
      for (int ks = 0; ks < 2; ks++)
        afr[i][ks] = *reinterpret_cast<const bf16x8*>(
            &sa[row * 64 + ((((ks << 2) | lg) ^ cx) << 3)]);
    }
    if (more) SGA(t + 1);
    __builtin_amdgcn_s_setprio(1);
#pragma unroll
    for (int i = 0; i < 4; i++)
#pragma unroll
      for (int n = 0; n < 4; n++) {
        acc[i][n] = __builtin_amdgcn_mfma_f32_16x16x32_bf16(afr[i][0], bfr[n][0], acc[i][n], 0, 0, 0);
        acc[i][n] = __builtin_amdgcn_mfma_f32_16x16x32_bf16(afr[i][1], bfr[n][1], acc[i][n], 0, 0, 0);
      }
    __builtin_amdgcn_s_setprio(0);
#pragma unroll
    for (int i = 0; i < 4; i++) {
      const int row = wr * 128 + 64 + i * 16 + lc;
#pragma unroll
      for (int ks = 0; ks < 2; ks++)
        afr[i][ks] = *reinterpret_cast<const bf16x8*>(
            &sa[row * 64 + ((((ks << 2) | lg) ^ cx) << 3)]);
    }
    if (more) SGB(t + 1);
    __builtin_amdgcn_s_setprio(1);
#pragma unroll
    for (int i = 0; i < 4; i++)
#pragma unroll
      for (int n = 0; n < 4; n++) {
        acc[4 + i][n] = __builtin_amdgcn_mfma_f32_16x16x32_bf16(afr[i][0], bfr[n][0], acc[4 + i][n], 0, 0, 0);
        acc[4 + i][n] = __builtin_amdgcn_mfma_f32_16x16x32_bf16(afr[i][1], bfr[n][1], acc[4 + i][n], 0, 0, 0);
      }
    __builtin_amdgcn_s_setprio(0);
    VMCNT0;
    __builtin_amdgcn_s_barrier();
  }
#undef SGA
#undef SGB

#pragma unroll
  for (int mi = 0; mi < 8; mi++)
#pragma unroll
    for (int ni = 0; ni < 4; ni++)
#pragma unroll
      for (int rg = 0; rg < 4; rg++) {
        const int row = bm + wr * 128 + mi * 16 + lg * 4 + rg;
        const int col = bn + wc * 64 + ni * 16 + lc;
        epi_store<EP>(acc[mi][ni][rg], (size_t)row * N + col, col, outf, res, scale, outb);
      }
}

// ---------------- gemmB: 128x128 tile, BK=64, 4 waves ----------------
template <int EP>
__global__ __launch_bounds__(256, 1) void gemmB(
    const u16* __restrict__ A, const u16* __restrict__ Bt,
    int M, int N, int K,
    float* __restrict__ outf, const float* __restrict__ res,
    const float* __restrict__ scale, u16* __restrict__ outb) {
  __shared__ u16 SA[2][128 * 64];
  __shared__ u16 SB[2][128 * 64];
  const int tid = threadIdx.x, lane = tid & 63, w = tid >> 6;  // 0..3
  const int wr = w >> 1, wc = w & 1;
  const int lg = lane >> 4, lc = lane & 15, cx = lc & 7;

  const int r8 = blockIdx.x & 7, j = blockIdx.x >> 3;
  const int bm = ((r8 << 2) + (j & 3)) << 7;   // M=4096: 32 m-blocks, 4 per XCD
  const int bn = (j >> 2) << 7;

  const int swrow = lane >> 3;
  const int swcol = (lane & 7) ^ swrow;
  const u16* gA = A + (size_t)(bm + w * 32 + swrow) * K + swcol * 8;
  const u16* gB = Bt + (size_t)(bn + w * 32 + swrow) * K + swcol * 8;

  const int NT = K >> 6;
  f32x4 acc[4][4] = {};

#define SG2(T_) do { int sl_ = (T_) & 1; size_t ko_ = (size_t)(T_) * 64; \
    GLDS(gA + ko_,                   &SA[sl_][(w * 32) * 64]); \
    GLDS(gA + ko_ + (size_t)8 * K,   &SA[sl_][(w * 32 + 8) * 64]); \
    GLDS(gA + ko_ + (size_t)16 * K,  &SA[sl_][(w * 32 + 16) * 64]); \
    GLDS(gA + ko_ + (size_t)24 * K,  &SA[sl_][(w * 32 + 24) * 64]); \
    GLDS(gB + ko_,                   &SB[sl_][(w * 32) * 64]); \
    GLDS(gB + ko_ + (size_t)8 * K,   &SB[sl_][(w * 32 + 8) * 64]); \
    GLDS(gB + ko_ + (size_t)16 * K,  &SB[sl_][(w * 32 + 16) * 64]); \
    GLDS(gB + ko_ + (size_t)24 * K,  &SB[sl_][(w * 32 + 24) * 64]); } while (0)

  SG2(0);
  VMCNT0;
  __builtin_amdgcn_s_barrier();

  for (int t = 0; t < NT; ++t) {
    const u16* sa = &SA[t & 1][0];
    const u16* sb = &SB[t & 1][0];
    const bool more = (t + 1 < NT);

    bf16x8 bfr[4][2], afr[4][2];
#pragma unroll
    for (int n = 0; n < 4; n++) {
      const int row = wc * 64 + n * 16 + lc;
#pragma unroll
      for (int ks = 0; ks < 2; ks++)
        bfr[n][ks] = *reinterpret_cast<const bf16x8*>(
            &sb[row * 64 + ((((ks << 2) | lg) ^ cx) << 3)]);
    }
#pragma unroll
    for (int i = 0; i < 4; i++) {
      const int row = wr * 64 + i * 16 + lc;
#pragma unroll
      for (int ks = 0; ks < 2; ks++)
        afr[i][ks] = *reinterpret_cast<const bf16x8*>(
            &sa[row * 64 + ((((ks << 2) | lg) ^ cx) << 3)]);
    }
    if (more) SG2(t + 1);
    __builtin_amdgcn_s_setprio(1);
#pragma unroll
    for (int i = 0; i < 4; i++)
#pragma unroll
      for (int n = 0; n < 4; n++) {
        acc[i][n] = __builtin_amdgcn_mfma_f32_16x16x32_bf16(afr[i][0], bfr[n][0], acc[i][n], 0, 0, 0);
        acc[i][n] = __builtin_amdgcn_mfma_f32_16x16x32_bf16(afr[i][1], bfr[n][1], acc[i][n], 0, 0, 0);
      }
    __builtin_amdgcn_s_setprio(0);
    VMCNT0;
    __builtin_amdgcn_s_barrier();
  }
#undef SG2

#pragma unroll
  for (int mi = 0; mi < 4; mi++)
#pragma unroll
    for (int ni = 0; ni < 4; ni++)
#pragma unroll
      for (int rg = 0; rg < 4; rg++) {
        const int row = bm + wr * 64 + mi * 16 + lg * 4 + rg;
        const int col = bn + wc * 64 + ni * 16 + lc;
        epi_store<EP>(acc[mi][ni][rg], (size_t)row * N + col, col, outf, res, scale, outb);
      }
}

// ---------------- RoPE: qkv f32 -> q_rope (pre-scaled by 0.125*log2e) bf16, k_rope bf16 ----------------
__global__ __launch_bounds__(256) void rope_kernel(
    const float* __restrict__ qkv, const float* __restrict__ cosb,
    const float* __restrict__ sinb, u16* __restrict__ qr, u16* __restrict__ kr) {
  int idx = blockIdx.x * 256 + threadIdx.x;  // B*S*20*32 total
  int d = idx & 31;
  int t = idx >> 5;
  int head = t % 20;
  int bs = t / 20;  // 0..4095
  int s = bs & (SEQ - 1);
  int b = bs >> 11;
  const float* row = qkv + (size_t)bs * 1536;
  float c = cosb[s * 32 + d], sn = sinb[s * 32 + d];
  const float QSC = 0.18033688011112042f;  // 0.125 * log2(e)
  float x1, x2;
  if (head < 16) {
    x1 = row[head * 64 + d];
    x2 = row[head * 64 + d + 32];
    size_t o = ((size_t)(b * NH + head) * SEQ + s) * 64 + d;
    qr[o] = f2bf((x1 * c + x2 * sn) * QSC);
    qr[o + 32] = f2bf((x2 * c - x1 * sn) * QSC);
  } else {
    int kh = head - 16;
    x1 = row[1024 + kh * 64 + d];
    x2 = row[1024 + kh * 64 + d + 32];
    size_t o = ((size_t)(b * NKV + kh) * SEQ + s) * 64 + d;
    kr[o] = f2bf(x1 * c + x2 * sn);
    kr[o + 32] = f2bf(x2 * c - x1 * sn);
  }
}

// ---------------- V transpose: qkv f32 -> vt [b][kv][d][s] bf16 ----------------
__global__ __launch_bounds__(256) void vtrans_kernel(
    const float* __restrict__ qkv, u16* __restrict__ vt) {
  int blk = blockIdx.x;
  int st = blk & 31; blk >>= 5;
  int kvh = blk & 3; blk >>= 2;
  int b = blk;
  __shared__ u16 tile[64][65];
  int tx = threadIdx.x & 63;
  int ty = threadIdx.x >> 6;  // 0..3
  int s0 = st * 64;
#pragma unroll
  for (int i = 0; i < 16; i++) {
    int sl = i * 4 + ty;
    tile[sl][tx] = f2bf(qkv[(size_t)(b * SEQ + s0 + sl) * 1536 + 1280 + kvh * 64 + tx]);
  }
  __syncthreads();
  size_t vbase = (size_t)(b * NKV + kvh) * 64 * SEQ;
#pragma unroll
  for (int i = 0; i < 16; i++) {
    int dd = i * 4 + ty;
    vt[vbase + (size_t)dd * SEQ + s0 + tx] = tile[tx][dd];
  }
}

// ---------------- Flash attention v7: dual-set waves, no barriers, no LDS ----------------
// 256 blocks x 4 waves. Wave w owns 32 q-rows of strip j (set A) AND 32 rows of
// strip 15-j (set B): per-wave tile work = (2j+2)+(32-2j) ~= uniform across ALL waves.
// K/V read directly from global (L1-shared within block, L2 within XCD).
__global__ __launch_bounds__(256, 1) void attn_kernel(
    const u16* __restrict__ qr, const u16* __restrict__ kr,
    const u16* __restrict__ vt, u16* __restrict__ out) {
  const int n = blockIdx.x;                 // 256 blocks
  const int g = n & 7;                      // b*4+kvh -> XCD-aligned
  const int b = g >> 2, kvh = g & 3;
  const int h = kvh * 4 + ((n >> 3) & 3);
  const int j = n >> 5;                     // 0..7

  const int tid = threadIdx.x;
  const int lane = tid & 63, w = tid >> 6;  // 4 waves
  const int l31 = lane & 31, hi = lane >> 5;

  const int qA0 = j * 128 + w * 32;         // light set
  const int qB0 = (15 - j) * 128 + w * 32;  // heavy set
  const int qgA = qA0 + l31, qgB = qB0 + l31;
  const int ntA = (qA0 >> 6) + 1;
  const int ntB = (qB0 >> 6) + 1;

  // Q fragments (B-operand, 32x32x16): qf[c][e] = Q[qg][16c + 8hi + e]
  bf16x8 qfA[4], qfB[4];
  {
    const u16* qpA = qr + ((size_t)(b * NH + h) * SEQ + qgA) * 64 + 8 * hi;
    const u16* qpB = qr + ((size_t)(b * NH + h) * SEQ + qgB) * 64 + 8 * hi;
#pragma unroll
    for (int c = 0; c < 4; c++) {
      qfA[c] = *reinterpret_cast<const bf16x8*>(qpA + 16 * c);
      qfB[c] = *reinterpret_cast<const bf16x8*>(qpB + 16 * c);
    }
  }

  // per-lane K/V base pointers
  const u16* kl = kr + (size_t)(b * NKV + kvh) * SEQ * 64 + (size_t)l31 * 64 + 8 * hi;
  const u16* vl = vt + (size_t)(b * NKV + kvh) * 64 * SEQ + (size_t)l31 * SEQ + 8 * hi;

  float mmA = -1e30f, llA = 0.0f, mmB = -1e30f, llB = 0.0f;
  f32x16 oA0 = {}, oA1 = {}, oB0 = {}, oB1 = {};

  for (int t = 0; t < ntB; ++t) {
    const int c0 = t * 64;
    const bool doA = (t < ntA);

    // K fragments (shared by both sets): kf[a][c] = K[c0+32a+l31][16c+8hi..]
    bf16x8 kf[2][4];
#pragma unroll
    for (int a = 0; a < 2; a++)
#pragma unroll
      for (int c = 0; c < 4; c++)
        kf[a][c] = *reinterpret_cast<const bf16x8*>(kl + (size_t)(c0 + 32 * a) * 64 + 16 * c);

    // V fragments (shared): vf[dch][c] = V[key=c0+16c+8hi..][d=dch*32+l31]
    bf16x8 vf[2][4];
#pragma unroll
    for (int dch = 0; dch < 2; dch++)
#pragma unroll
      for (int c = 0; c < 4; c++)
        vf[dch][c] = *reinterpret_cast<const bf16x8*>(vl + (size_t)dch * 32 * SEQ + c0 + 16 * c);

    // QK^T for both sets
    f32x16 scA0 = {}, scA1 = {}, scB0 = {}, scB1 = {};
#pragma unroll
    for (int c = 0; c < 4; c++) {
      scB0 = __builtin_amdgcn_mfma_f32_32x32x16_bf16(kf[0][c], qfB[c], scB0, 0, 0, 0);
      scB1 = __builtin_amdgcn_mfma_f32_32x32x16_bf16(kf[1][c], qfB[c], scB1, 0, 0, 0);
    }
    if (doA) {
#pragma unroll
      for (int c = 0; c < 4; c++) {
        scA0 = __builtin_amdgcn_mfma_f32_32x32x16_bf16(kf[0][c], qfA[c], scA0, 0, 0, 0);
        scA1 = __builtin_amdgcn_mfma_f32_32x32x16_bf16(kf[1][c], qfA[c], scA1, 0, 0, 0);
      }
    }

#define SOFTMAX_PV(scx0, scx1, qg_, q0_, mm_, ll_, o0_, o1_)                 \
    do {                                                                     \
      if (c0 + 63 > (q0_)) {                                                 \
        _Pragma("unroll") for (int r = 0; r < 16; r++) {                     \
          const int krow = (r & 3) + 8 * (r >> 2) + 4 * hi;                  \
          if (c0 + krow > (qg_)) scx0[r] = -1e30f;                           \
          if (c0 + 32 + krow > (qg_)) scx1[r] = -1e30f;                      \
        }                                                                    \
      }                                                                      \
      float mx = -1e30f;                                                     \
      _Pragma("unroll") for (int r = 0; r < 16; r++) {                       \
        mx = fmaxf(mx, scx0[r]);                                             \
        mx = fmaxf(mx, scx1[r]);                                             \
      }                                                                      \
      mx = fmaxf(mx, __shfl_xor(mx, 32));                                    \
      if (!__all(mx - (mm_) <= 11.5f)) {                                     \
        float mn = fmaxf((mm_), mx);                                         \
        float al = exp2f((mm_) - mn);                                        \
        (mm_) = mn;                                                          \
        (ll_) *= al;                                                         \
        _Pragma("unroll") for (int r = 0; r < 16; r++) {                     \
          float arr = __shfl(al, (r & 3) + 8 * (r >> 2) + 4 * hi);           \
          o0_[r] *= arr;                                                     \
          o1_[r] *= arr;                                                     \
        }                                                                    \
      }                                                                      \
      float rs = 0.0f;                                                       \
      _Pragma("unroll") for (int r = 0; r < 16; r++) {                       \
        float p0 = exp2f(scx0[r] - (mm_));                                   \
        float p1 = exp2f(scx1[r] - (mm_));                                   \
        scx0[r] = p0;                                                        \
        scx1[r] = p1;                                                        \
        rs += p0 + p1;                                                       \
      }                                                                      \
      rs += __shfl_xor(rs, 32);                                              \
      (ll_) += rs;                                                           \
      bf16x8 pa[4];                                                          \
      _Pragma("unroll") for (int c = 0; c < 4; c++) {                        \
        const int bb = 8 * (c & 1);                                          \
        u32 A0, A1, B0, B1;                                                  \
        if (c < 2) {                                                         \
          A0 = pk2(scx0[bb + 0], scx0[bb + 1]);                              \
          A1 = pk2(scx0[bb + 2], scx0[bb + 3]);                              \
          B0 = pk2(scx0[bb + 4], scx0[bb + 5]);                              \
          B1 = pk2(scx0[bb + 6], scx0[bb + 7]);                              \
        } else {                                                             \
          A0 = pk2(scx1[bb + 0], scx1[bb + 1]);                              \
          A1 = pk2(scx1[bb + 2], scx1[bb + 3]);                              \
          B0 = pk2(scx1[bb + 4], scx1[bb + 5]);                              \
          B1 = pk2(scx1[bb + 6], scx1[bb + 7]);                              \
        }                                                                    \
        u32 s0 = hi ? A0 : B0;                                               \
        u32 s1 = hi ? A1 : B1;                                               \
        u32 r0 = (u32)__shfl_xor((int)s0, 32);                               \
        u32 r1 = (u32)__shfl_xor((int)s1, 32);                               \
        uint4 pw;                                                            \
        pw.x = hi ? r0 : A0;                                                 \
        pw.y = hi ? r1 : A1;                                                 \
        pw.z = hi ? B0 : r0;                                                 \
        pw.w = hi ? B1 : r1;                                                 \
        pa[c] = __builtin_bit_cast(bf16x8, pw);                              \
      }                                                                      \
      _Pragma("unroll") for (int c = 0; c < 4; c++) {                        \
        o0_ = __builtin_amdgcn_mfma_f32_32x32x16_bf16(pa[c], vf[0][c], o0_, 0, 0, 0); \
        o1_ = __builtin_amdgcn_mfma_f32_32x32x16_bf16(pa[c], vf[1][c], o1_, 0, 0, 0); \
      }                                                                      \
    } while (0)

    SOFTMAX_PV(scB0, scB1, qgB, qB0, mmB, llB, oB0, oB1);
    if (doA) SOFTMAX_PV(scA0, scA1, qgA, qA0, mmA, llA, oA0, oA1);
#undef SOFTMAX_PV
  }

  // epilogue: write both sets
#define WRITE_SET(q0_, ll_, o0_, o1_)                                        \
  do {                                                                       \
    const float li = 1.0f / (ll_);                                           \
    _Pragma("unroll") for (int r = 0; r < 16; r++) {                         \
      const int qloc = (r & 3) + 8 * (r >> 2) + 4 * hi;                      \
      float liq = __shfl(li, qloc);                                          \
      const int q = (q0_) + qloc;                                            \
      u16* orow = out + (size_t)(b * SEQ + q) * 1024 + h * 64 + l31;         \
      orow[0] = f2bf(o0_[r] * liq);                                          \
      orow[32] = f2bf(o1_[r] * liq);                                         \
    }                                                                        \
  } while (0)

  WRITE_SET(qA0, llA, oA0, oA1);
  WRITE_SET(qB0, llB, oB0, oB1);
#undef WRITE_SET
}

extern "C" void kernel_launch(void* const* d_in, const int* in_sizes, int n_in,
                              void* d_out, int out_size, void* d_ws, size_t ws_size,
                              hipStream_t stream) {
  const float* x = (const float*)d_in[0];
  const float* w_norm1 = (const float*)d_in[1];
  const float* wq = (const float*)d_in[2];
  const float* wk = (const float*)d_in[3];
  const float* wv = (const float*)d_in[4];
  const float* wo = (const float*)d_in[5];
  const float* attn_scale = (const float*)d_in[6];
  const float* w_norm2 = (const float*)d_in[7];
  const float* wg = (const float*)d_in[8];
  const float* wu = (const float*)d_in[9];
  const float* wd = (const float*)d_in[10];
  const float* mlp_scale = (const float*)d_in[11];
  const float* cosb = (const float*)d_in[12];
  const float* sinb = (const float*)d_in[13];
  float* out = (float*)d_out;

  char* ws = (char*)d_ws;
  u16* wqkv_t = (u16*)(ws + 0);            // 1536x1024 bf16
  u16* wo_t = (u16*)(ws + 3145728);        // 1024x1024 bf16
  u16* wg_t = (u16*)(ws + 5242880);        // 4096x1024 bf16
  u16* wu_t = (u16*)(ws + 13631488);
  u16* wd_t = (u16*)(ws + 22020096);       // 1024x4096 bf16
  u16* xn = (u16*)(ws + 30408704);         // 4096x1024 bf16 (reused for xn2)
  float* qkv = (float*)(ws + 38797312);    // 4096x1536 f32
  u16* attn_o = (u16*)(ws + 38797312);     // alias (qkv dead)
  float* x1 = (float*)(ws + 47185920);     // 4096x1024 f32
  u16* q_rope = (u16*)(ws + 63963136);     // 2*16*2048*64 bf16
  u16* k_rope = (u16*)(ws + 72351744);     // 2*4*2048*64 bf16
  u16* vt = (u16*)(ws + 74448896);         // 2*4*64*2048 bf16
  u16* hbuf = (u16*)(ws + 63963136);       // alias (rope dead in FFN phase)

  dim3 tb(256);
  transpose_cast_kernel<<<dim3(32, 32), tb, 0, stream>>>(wq, wqkv_t, 1024, 1024);
  transpose_cast_kernel<<<dim3(8, 32), tb, 0, stream>>>(wk, wqkv_t + (size_t)1024 * 1024, 1024, 256);
  transpose_cast_kernel<<<dim3(8, 32), tb, 0, stream>>>(wv, wqkv_t + (size_t)1280 * 1024, 1024, 256);
  transpose_cast_kernel<<<dim3(32, 32), tb, 0, stream>>>(wo, wo_t, 1024, 1024);
  transpose_cast_kernel<<<dim3(128, 32), tb, 0, stream>>>(wg, wg_t, 1024, 4096);
  transpose_cast_kernel<<<dim3(128, 32), tb, 0, stream>>>(wu, wu_t, 1024, 4096);
  transpose_cast_kernel<<<dim3(32, 128), tb, 0, stream>>>(wd, wd_t, 4096, 1024);

  rmsnorm_kernel<<<4096, tb, 0, stream>>>(x, w_norm1, xn);
  gemmB<0><<<dim3(384), dim3(256), 0, stream>>>(xn, wqkv_t, 4096, 1536, 1024, qkv, nullptr, nullptr, nullptr);
  rope_kernel<<<10240, tb, 0, stream>>>(qkv, cosb, sinb, q_rope, k_rope);
  vtrans_kernel<<<2 * 4 * 32, tb, 0, stream>>>(qkv, vt);
  attn_kernel<<<256, dim3(256), 0, stream>>>(q_rope, k_rope, vt, attn_o);
  gemmB<1><<<dim3(256), dim3(256), 0, stream>>>(attn_o, wo_t, 4096, 1024, 1024, x1, x, attn_scale, nullptr);
  rmsnorm_kernel<<<4096, tb, 0, stream>>>(x1, w_norm2, xn);
  gemmA<2><<<dim3(256), dim3(512), 0, stream>>>(xn, wg_t, 4096, 4096, 1024, nullptr, nullptr, nullptr, hbuf);
  gemmA<3><<<dim3(256), dim3(512), 0, stream>>>(xn, wu_t, 4096, 4096, 1024, nullptr, nullptr, nullptr, hbuf);
  gemmB<1><<<dim3(256), dim3(256), 0, stream>>>(hbuf, wd_t, 4096, 1024, 4096, out, x1, mlp_scale, nullptr);
}

// Round 11
// 291.514 us; speedup vs baseline: 1.0422x; 1.0005x over previous
//
#include <hip/hip_runtime.h>
#include <hip/hip_bf16.h>
#include <cstdint>

typedef unsigned short u16;
typedef unsigned int u32;
typedef __attribute__((ext_vector_type(4))) float f32x4;
typedef __attribute__((ext_vector_type(16))) float f32x16;
typedef __attribute__((ext_vector_type(8))) __bf16 bf16x8;

#define NH 16
#define NKV 4
#define SEQ 2048
#define NTOK 4096

__device__ inline u16 f2bf(float f) {
  return __builtin_bit_cast(u16, __float2bfloat16(f));
}
__device__ inline float bf2f(u16 u) {
  return __bfloat162float(__builtin_bit_cast(__hip_bfloat16, u));
}
__device__ inline u32 pk2(float a, float b) {
  return (u32)f2bf(a) | ((u32)f2bf(b) << 16);
}

#define GLDS(gp, lp) __builtin_amdgcn_global_load_lds( \
    (__attribute__((address_space(1))) void*)(gp), \
    (__attribute__((address_space(3))) void*)(lp), 16, 0, 0)

#define VMCNT0 asm volatile("s_waitcnt vmcnt(0)" ::: "memory")

// ---------------- RMSNorm (f32 in, bf16 out) ----------------
__global__ __launch_bounds__(256) void rmsnorm_kernel(
    const float* __restrict__ x, const float* __restrict__ w,
    u16* __restrict__ out) {
  int row = blockIdx.x;
  int tid = threadIdx.x;
  const float4 v = reinterpret_cast<const float4*>(x + (size_t)row * 1024)[tid];
  float ss = v.x * v.x + v.y * v.y + v.z * v.z + v.w * v.w;
#pragma unroll
  for (int off = 32; off; off >>= 1) ss += __shfl_xor(ss, off);
  __shared__ float red[4];
  int lane = tid & 63, wid = tid >> 6;
  if (lane == 0) red[wid] = ss;
  __syncthreads();
  float tot = red[0] + red[1] + red[2] + red[3];
  float r = rsqrtf(tot * (1.0f / 1024.0f) + 1e-6f);
  const float4 wv = reinterpret_cast<const float4*>(w)[tid];
  ushort4 o;
  o.x = f2bf(v.x * r * wv.x);
  o.y = f2bf(v.y * r * wv.y);
  o.z = f2bf(v.z * r * wv.z);
  o.w = f2bf(v.w * r * wv.w);
  reinterpret_cast<ushort4*>(out + (size_t)row * 1024)[tid] = o;
}

// ---------------- weight transpose + cast: src[K][N] f32 -> dst[N][K] bf16 ----------------
__global__ __launch_bounds__(256) void transpose_cast_kernel(
    const float* __restrict__ src, u16* __restrict__ dst, int K, int N) {
  __shared__ float tile[32][33];
  int n0 = blockIdx.x * 32, k0 = blockIdx.y * 32;
  int tx = threadIdx.x & 31, ty = threadIdx.x >> 5;  // ty: 0..7
#pragma unroll
  for (int i = 0; i < 4; i++)
    tile[ty + i * 8][tx] = src[(size_t)(k0 + ty + i * 8) * N + n0 + tx];
  __syncthreads();
#pragma unroll
  for (int i = 0; i < 4; i++)
    dst[(size_t)(n0 + ty + i * 8) * K + k0 + tx] = f2bf(tile[tx][ty + i * 8]);
}

// Shared epilogue
template <int EP>
__device__ inline void epi_store(float v, size_t idx, int col,
                                 float* __restrict__ outf,
                                 const float* __restrict__ res,
                                 const float* __restrict__ scale,
                                 u16* __restrict__ outb) {
  if (EP == 0) {
    outf[idx] = v;
  } else if (EP == 1) {
    outf[idx] = res[idx] + v * scale[col];
  } else if (EP == 2) {
    outb[idx] = f2bf(v / (1.0f + __expf(-v)));
  } else {
    outb[idx] = f2bf(bf2f(outb[idx]) * v);
  }
}

// ---------------- gemmA: 256x256 tile, BK=64, 8 waves, 1 barrier/tile ----------------
template <int EP>
__global__ __launch_bounds__(512, 1) void gemmA(
    const u16* __restrict__ A, const u16* __restrict__ Bt,
    int M, int N, int K,
    float* __restrict__ outf, const float* __restrict__ res,
    const float* __restrict__ scale, u16* __restrict__ outb) {
  __shared__ u16 SA[2][256 * 64];
  __shared__ u16 SB[2][256 * 64];
  const int tid = threadIdx.x, lane = tid & 63, w = tid >> 6;
  const int wr = w >> 2, wc = w & 3;
  const int lg = lane >> 4, lc = lane & 15, cx = lc & 7;

  const int nbn = N >> 8;  // 16 for gate/up
  const int r8 = blockIdx.x & 7, j = blockIdx.x >> 3;
  const int bm = (((r8 >> 1) << 2) + (j & 3)) << 8;
  const int bn = ((r8 & 1) * (nbn >> 1) + (j >> 2)) << 8;

  const int swrow = lane >> 3;                 // 0..7
  const int swcol = (lane & 7) ^ swrow;        // pre-swizzled source chunk
  const u16* gA = A + (size_t)(bm + w * 16 + swrow) * K + swcol * 8;
  const u16* gB = Bt + (size_t)(bn + w * 16 + swrow) * K + swcol * 8;

  const int NT = K >> 6;
  f32x4 acc[8][4] = {};

#define SGA(T_) do { int sl_ = (T_) & 1; size_t ko_ = (size_t)(T_) * 64; \
    GLDS(gA + ko_,                    &SA[sl_][(w * 16) * 64]); \
    GLDS(gA + ko_ + (size_t)8 * K,    &SA[sl_][(w * 16 + 8) * 64]); \
    GLDS(gA + ko_ + (size_t)128 * K,  &SA[sl_][(128 + w * 16) * 64]); \
    GLDS(gA + ko_ + (size_t)136 * K,  &SA[sl_][(136 + w * 16) * 64]); } while (0)
#define SGB(T_) do { int sl_ = (T_) & 1; size_t ko_ = (size_t)(T_) * 64; \
    GLDS(gB + ko_,                    &SB[sl_][(w * 16) * 64]); \
    GLDS(gB + ko_ + (size_t)8 * K,    &SB[sl_][(w * 16 + 8) * 64]); \
    GLDS(gB + ko_ + (size_t)128 * K,  &SB[sl_][(128 + w * 16) * 64]); \
    GLDS(gB + ko_ + (size_t)136 * K,  &SB[sl_][(136 + w * 16) * 64]); } while (0)

  SGA(0);
  SGB(0);
  VMCNT0;
  __builtin_amdgcn_s_barrier();

  for (int t = 0; t < NT; ++t) {
    const u16* sa = &SA[t & 1][0];
    const u16* sb = &SB[t & 1][0];
    const bool more = (t + 1 < NT);

    bf16x8 bfr[4][2];
#pragma unroll
    for (int n = 0; n < 4; n++) {
      const int row = wc * 64 + n * 16 + lc;
#pragma unroll
      for (int ks = 0; ks < 2; ks++)
        bfr[n][ks] = *reinterpret_cast<const bf16x8*>(
            &sb[row * 64 + ((((ks << 2) | lg) ^ cx) << 3)]);
    }
    bf16x8 afr[4][2];
#pragma unroll
    for (int i = 0; i < 4; i++) {
      const int row = wr * 128 + i * 16 + lc;
#pragma unroll
      for (int ks = 0; ks < 2; ks++)
        afr[i][ks] = *reinterpret_cast<const bf16x8*>(
            &sa[row * 64 + ((((ks << 2) | lg) ^ cx) << 3)]);
    }
    if (more) SGA(t + 1);
    __builtin_amdgcn_s_setprio(1);
#pragma unroll
    for (int i = 0; i < 4; i++)
#pragma unroll
      for (int n = 0; n < 4; n++) {
        acc[i][n] = __builtin_amdgcn_mfma_f32_16x16x32_bf16(afr[i][0], bfr[n][0], acc[i][n], 0, 0, 0);
        acc[i][n] = __builtin_amdgcn_mfma_f32_16x16x32_bf16(afr[i][1], bfr[n][1], acc[i][n], 0, 0, 0);
      }
    __builtin_amdgcn_s_setprio(0);
#pragma unroll
    for (int i = 0; i < 4; i++) {
      const int row = wr * 128 + 64 + i * 16 + lc;
#pragma unroll
      for (int ks = 0; ks < 2; ks++)
        afr[i][ks] = *reinterpret_cast<const bf16x8*>(
            &sa[row * 64 + ((((ks << 2) | lg) ^ cx) << 3)]);
    }
    if (more) SGB(t + 1);
    __builtin_amdgcn_s_setprio(1);
#pragma unroll
    for (int i = 0; i < 4; i++)
#pragma unroll
      for (int n = 0; n < 4; n++) {
        acc[4 + i][n] = __builtin_amdgcn_mfma_f32_16x16x32_bf16(afr[i][0], bfr[n][0], acc[4 + i][n], 0, 0, 0);
        acc[4 + i][n] = __builtin_amdgcn_mfma_f32_16x16x32_bf16(afr[i][1], bfr[n][1], acc[4 + i][n], 0, 0, 0);
      }
    __builtin_amdgcn_s_setprio(0);
    VMCNT0;
    __builtin_amdgcn_s_barrier();
  }
#undef SGA
#undef SGB

#pragma unroll
  for (int mi = 0; mi < 8; mi++)
#pragma unroll
    for (int ni = 0; ni < 4; ni++)
#pragma unroll
      for (int rg = 0; rg < 4; rg++) {
        const int row = bm + wr * 128 + mi * 16 + lg * 4 + rg;
        const int col = bn + wc * 64 + ni * 16 + lc;
        epi_store<EP>(acc[mi][ni][rg], (size_t)row * N + col, col, outf, res, scale, outb);
      }
}

// ---------------- gemmB: 128x128 tile, BK=64, 4 waves ----------------
template <int EP>
__global__ __launch_bounds__(256, 1) void gemmB(
    const u16* __restrict__ A, const u16* __restrict__ Bt,
    int M, int N, int K,
    float* __restrict__ outf, const float* __restrict__ res,
    const float* __restrict__ scale, u16* __restrict__ outb) {
  __shared__ u16 SA[2][128 * 64];
  __shared__ u16 SB[2][128 * 64];
  const int tid = threadIdx.x, lane = tid & 63, w = tid >> 6;  // 0..3
  const int wr = w >> 1, wc = w & 1;
  const int lg = lane >> 4, lc = lane & 15, cx = lc & 7;

  const int r8 = blockIdx.x & 7, j = blockIdx.x >> 3;
  const int bm = ((r8 << 2) + (j & 3)) << 7;   // M=4096: 32 m-blocks, 4 per XCD
  const int bn = (j >> 2) << 7;

  const int swrow = lane >> 3;
  const int swcol = (lane & 7) ^ swrow;
  const u16* gA = A + (size_t)(bm + w * 32 + swrow) * K + swcol * 8;
  const u16* gB = Bt + (size_t)(bn + w * 32 + swrow) * K + swcol * 8;

  const int NT = K >> 6;
  f32x4 acc[4][4] = {};

#define SG2(T_) do { int sl_ = (T_) & 1; size_t ko_ = (size_t)(T_) * 64; \
    GLDS(gA + ko_,                   &SA[sl_][(w * 32) * 64]); \
    GLDS(gA + ko_ + (size_t)8 * K,   &SA[sl_][(w * 32 + 8) * 64]); \
    GLDS(gA + ko_ + (size_t)16 * K,  &SA[sl_][(w * 32 + 16) * 64]); \
    GLDS(gA + ko_ + (size_t)24 * K,  &SA[sl_][(w * 32 + 24) * 64]); \
    GLDS(gB + ko_,                   &SB[sl_][(w * 32) * 64]); \
    GLDS(gB + ko_ + (size_t)8 * K,   &SB[sl_][(w * 32 + 8) * 64]); \
    GLDS(gB + ko_ + (size_t)16 * K,  &SB[sl_][(w * 32 + 16) * 64]); \
    GLDS(gB + ko_ + (size_t)24 * K,  &SB[sl_][(w * 32 + 24) * 64]); } while (0)

  SG2(0);
  VMCNT0;
  __builtin_amdgcn_s_barrier();

  for (int t = 0; t < NT; ++t) {
    const u16* sa = &SA[t & 1][0];
    const u16* sb = &SB[t & 1][0];
    const bool more = (t + 1 < NT);

    bf16x8 bfr[4][2], afr[4][2];
#pragma unroll
    for (int n = 0; n < 4; n++) {
      const int row = wc * 64 + n * 16 + lc;
#pragma unroll
      for (int ks = 0; ks < 2; ks++)
        bfr[n][ks] = *reinterpret_cast<const bf16x8*>(
            &sb[row * 64 + ((((ks << 2) | lg) ^ cx) << 3)]);
    }
#pragma unroll
    for (int i = 0; i < 4; i++) {
      const int row = wr * 64 + i * 16 + lc;
#pragma unroll
      for (int ks = 0; ks < 2; ks++)
        afr[i][ks] = *reinterpret_cast<const bf16x8*>(
            &sa[row * 64 + ((((ks << 2) | lg) ^ cx) << 3)]);
    }
    if (more) SG2(t + 1);
    __builtin_amdgcn_s_setprio(1);
#pragma unroll
    for (int i = 0; i < 4; i++)
#pragma unroll
      for (int n = 0; n < 4; n++) {
        acc[i][n] = __builtin_amdgcn_mfma_f32_16x16x32_bf16(afr[i][0], bfr[n][0], acc[i][n], 0, 0, 0);
        acc[i][n] = __builtin_amdgcn_mfma_f32_16x16x32_bf16(afr[i][1], bfr[n][1], acc[i][n], 0, 0, 0);
      }
    __builtin_amdgcn_s_setprio(0);
    VMCNT0;
    __builtin_amdgcn_s_barrier();
  }
#undef SG2

#pragma unroll
  for (int mi = 0; mi < 4; mi++)
#pragma unroll
    for (int ni = 0; ni < 4; ni++)
#pragma unroll
      for (int rg = 0; rg < 4; rg++) {
        const int row = bm + wr * 64 + mi * 16 + lg * 4 + rg;
        const int col = bn + wc * 64 + ni * 16 + lc;
        epi_store<EP>(acc[mi][ni][rg], (size_t)row * N + col, col, outf, res, scale, outb);
      }
}

// ---------------- RoPE: qkv f32 -> q_rope (pre-scaled by 0.125*log2e) bf16, k_rope bf16 ----------------
__global__ __launch_bounds__(256) void rope_kernel(
    const float* __restrict__ qkv, const float* __restrict__ cosb,
    const float* __restrict__ sinb, u16* __restrict__ qr, u16* __restrict__ kr) {
  int idx = blockIdx.x * 256 + threadIdx.x;  // B*S*20*32 total
  int d = idx & 31;
  int t = idx >> 5;
  int head = t % 20;
  int bs = t / 20;  // 0..4095
  int s = bs & (SEQ - 1);
  int b = bs >> 11;
  const float* row = qkv + (size_t)bs * 1536;
  float c = cosb[s * 32 + d], sn = sinb[s * 32 + d];
  const float QSC = 0.18033688011112042f;  // 0.125 * log2(e)
  float x1, x2;
  if (head < 16) {
    x1 = row[head * 64 + d];
    x2 = row[head * 64 + d + 32];
    size_t o = ((size_t)(b * NH + head) * SEQ + s) * 64 + d;
    qr[o] = f2bf((x1 * c + x2 * sn) * QSC);
    qr[o + 32] = f2bf((x2 * c - x1 * sn) * QSC);
  } else {
    int kh = head - 16;
    x1 = row[1024 + kh * 64 + d];
    x2 = row[1024 + kh * 64 + d + 32];
    size_t o = ((size_t)(b * NKV + kh) * SEQ + s) * 64 + d;
    kr[o] = f2bf(x1 * c + x2 * sn);
    kr[o + 32] = f2bf(x2 * c - x1 * sn);
  }
}

// ---------------- V transpose: qkv f32 -> vt [b][kv][d][s] bf16 ----------------
__global__ __launch_bounds__(256) void vtrans_kernel(
    const float* __restrict__ qkv, u16* __restrict__ vt) {
  int blk = blockIdx.x;
  int st = blk & 31; blk >>= 5;
  int kvh = blk & 3; blk >>= 2;
  int b = blk;
  __shared__ u16 tile[64][65];
  int tx = threadIdx.x & 63;
  int ty = threadIdx.x >> 6;  // 0..3
  int s0 = st * 64;
#pragma unroll
  for (int i = 0; i < 16; i++) {
    int sl = i * 4 + ty;
    tile[sl][tx] = f2bf(qkv[(size_t)(b * SEQ + s0 + sl) * 1536 + 1280 + kvh * 64 + tx]);
  }
  __syncthreads();
  size_t vbase = (size_t)(b * NKV + kvh) * 64 * SEQ;
#pragma unroll
  for (int i = 0; i < 16; i++) {
    int dd = i * 4 + ty;
    vt[vbase + (size_t)dd * SEQ + s0 + tx] = tile[tx][dd];
  }
}

// ---------------- attention core span: rows [q0, q0+32), key tiles [t0, t1) ----------------
__device__ __forceinline__ void attn_span(
    const u16* __restrict__ kl, const u16* __restrict__ vl,
    const bf16x8 qf[4], int t0, int t1, int q0, int hi, int l31,
    float& mm, float& ll, f32x16& o0, f32x16& o1) {
  const int qg = q0 + l31;
  for (int t = t0; t < t1; ++t) {
    const int c0 = t * 64;
    bf16x8 kf[2][4];
#pragma unroll
    for (int a = 0; a < 2; a++)
#pragma unroll
      for (int c = 0; c < 4; c++)
        kf[a][c] = *reinterpret_cast<const bf16x8*>(kl + (size_t)(c0 + 32 * a) * 64 + 16 * c);
    bf16x8 vf[2][4];
#pragma unroll
    for (int dch = 0; dch < 2; dch++)
#pragma unroll
      for (int c = 0; c < 4; c++)
        vf[dch][c] = *reinterpret_cast<const bf16x8*>(vl + (size_t)dch * 32 * SEQ + c0 + 16 * c);

    f32x16 sc0 = {}, sc1 = {};
#pragma unroll
    for (int c = 0; c < 4; c++) {
      sc0 = __builtin_amdgcn_mfma_f32_32x32x16_bf16(kf[0][c], qf[c], sc0, 0, 0, 0);
      sc1 = __builtin_amdgcn_mfma_f32_32x32x16_bf16(kf[1][c], qf[c], sc1, 0, 0, 0);
    }

    if (c0 + 63 > q0) {
#pragma unroll
      for (int r = 0; r < 16; r++) {
        const int krow = (r & 3) + 8 * (r >> 2) + 4 * hi;
        if (c0 + krow > qg) sc0[r] = -1e30f;
        if (c0 + 32 + krow > qg) sc1[r] = -1e30f;
      }
    }

    float mx = -1e30f;
#pragma unroll
    for (int r = 0; r < 16; r++) {
      mx = fmaxf(mx, sc0[r]);
      mx = fmaxf(mx, sc1[r]);
    }
    mx = fmaxf(mx, __shfl_xor(mx, 32));

    if (!__all(mx - mm <= 11.5f)) {
      float mn = fmaxf(mm, mx);
      float al = exp2f(mm - mn);
      mm = mn;
      ll *= al;
#pragma unroll
      for (int r = 0; r < 16; r++) {
        float arr = __shfl(al, (r & 3) + 8 * (r >> 2) + 4 * hi);
        o0[r] *= arr;
        o1[r] *= arr;
      }
    }

    float rs = 0.0f;
#pragma unroll
    for (int r = 0; r < 16; r++) {
      float p0 = exp2f(sc0[r] - mm);
      float p1 = exp2f(sc1[r] - mm);
      sc0[r] = p0;
      sc1[r] = p1;
      rs += p0 + p1;
    }
    rs += __shfl_xor(rs, 32);
    ll += rs;

    bf16x8 pa[4];
#pragma unroll
    for (int c = 0; c < 4; c++) {
      const int bb = 8 * (c & 1);
      u32 A0, A1, B0, B1;
      if (c < 2) {
        A0 = pk2(sc0[bb + 0], sc0[bb + 1]);
        A1 = pk2(sc0[bb + 2], sc0[bb + 3]);
        B0 = pk2(sc0[bb + 4], sc0[bb + 5]);
        B1 = pk2(sc0[bb + 6], sc0[bb + 7]);
      } else {
        A0 = pk2(sc1[bb + 0], sc1[bb + 1]);
        A1 = pk2(sc1[bb + 2], sc1[bb + 3]);
        B0 = pk2(sc1[bb + 4], sc1[bb + 5]);
        B1 = pk2(sc1[bb + 6], sc1[bb + 7]);
      }
      u32 s0 = hi ? A0 : B0;
      u32 s1 = hi ? A1 : B1;
      u32 r0 = (u32)__shfl_xor((int)s0, 32);
      u32 r1 = (u32)__shfl_xor((int)s1, 32);
      uint4 pw;
      pw.x = hi ? r0 : A0;
      pw.y = hi ? r1 : A1;
      pw.z = hi ? B0 : r0;
      pw.w = hi ? B1 : r1;
      pa[c] = __builtin_bit_cast(bf16x8, pw);
    }
#pragma unroll
    for (int c = 0; c < 4; c++) {
      o0 = __builtin_amdgcn_mfma_f32_32x32x16_bf16(pa[c], vf[0][c], o0, 0, 0, 0);
      o1 = __builtin_amdgcn_mfma_f32_32x32x16_bf16(pa[c], vf[1][c], o1, 0, 0, 0);
    }
  }
}

// ---------------- Flash attention v8: split-K pairing, 8 waves, 2 waves/SIMD ----------------
// Wave (sub, role): role0 = light strip full + heavy strip tail; role1 = heavy strip head.
// Every wave does 16-17 tiles. Heavy partials merged via LDS (online-softmax merge).
__global__ __launch_bounds__(512, 2) void attn_kernel(
    const u16* __restrict__ qr, const u16* __restrict__ kr,
    const u16* __restrict__ vt, u16* __restrict__ out) {
  __shared__ float pO[4][32][64];
  __shared__ float pM[4][32];
  __shared__ float pL[4][32];

  const int n = blockIdx.x;                 // 256 blocks
  const int g = n & 7;                      // b*4+kvh -> XCD-aligned
  const int b = g >> 2, kvh = g & 3;
  const int h = kvh * 4 + ((n >> 3) & 3);
  const int j = n >> 5;                     // 0..7

  const int tid = threadIdx.x;
  const int lane = tid & 63, w = tid >> 6;  // 8 waves
  const int l31 = lane & 31, hi = lane >> 5;
  const int sub = w & 3, role = w >> 2;

  const int qL0 = j * 128 + sub * 32;        // light rows
  const int qH0 = (15 - j) * 128 + sub * 32; // heavy rows
  const int TL = (qL0 >> 6) + 1;
  const int TH = (qH0 >> 6) + 1;
  const int S = (TL + TH) >> 1;              // split point (role1: [0,S), role0 tail: [S,TH))

  const u16* kl = kr + (size_t)(b * NKV + kvh) * SEQ * 64 + (size_t)l31 * 64 + 8 * hi;
  const u16* vl = vt + (size_t)(b * NKV + kvh) * 64 * SEQ + (size_t)l31 * SEQ + 8 * hi;
  const u16* qbase = qr + (size_t)(b * NH + h) * SEQ * 64 + 8 * hi;

  float mmH = -1e30f, llH = 0.0f;
  f32x16 oH0 = {}, oH1 = {};

  if (role == 0) {
    // --- light rows, full range ---
    bf16x8 qf[4];
    {
      const u16* qp = qbase + (size_t)(qL0 + l31) * 64;
#pragma unroll
      for (int c = 0; c < 4; c++) qf[c] = *reinterpret_cast<const bf16x8*>(qp + 16 * c);
    }
    float mm = -1e30f, ll = 0.0f;
    f32x16 o0 = {}, o1 = {};
    attn_span(kl, vl, qf, 0, TL, qL0, hi, l31, mm, ll, o0, o1);
    {
      const float li = 1.0f / ll;
#pragma unroll
      for (int r = 0; r < 16; r++) {
        const int qloc = (r & 3) + 8 * (r >> 2) + 4 * hi;
        float liq = __shfl(li, qloc);
        u16* orow = out + (size_t)(b * SEQ + qL0 + qloc) * 1024 + h * 64 + l31;
        orow[0] = f2bf(o0[r] * liq);
        orow[32] = f2bf(o1[r] * liq);
      }
    }
    // --- heavy rows, tail [S, TH) ---
    bf16x8 qfH[4];
    {
      const u16* qp = qbase + (size_t)(qH0 + l31) * 64;
#pragma unroll
      for (int c = 0; c < 4; c++) qfH[c] = *reinterpret_cast<const bf16x8*>(qp + 16 * c);
    }
    attn_span(kl, vl, qfH, S, TH, qH0, hi, l31, mmH, llH, oH0, oH1);
  } else {
    // --- heavy rows, head [0, S) (provably unmasked) ---
    bf16x8 qfH[4];
    {
      const u16* qp = qbase + (size_t)(qH0 + l31) * 64;
#pragma unroll
      for (int c = 0; c < 4; c++) qfH[c] = *reinterpret_cast<const bf16x8*>(qp + 16 * c);
    }
    attn_span(kl, vl, qfH, 0, S, qH0, hi, l31, mmH, llH, oH0, oH1);
    // write partials to LDS
#pragma unroll
    for (int r = 0; r < 16; r++) {
      const int qloc = (r & 3) + 8 * (r >> 2) + 4 * hi;
      pO[sub][qloc][l31] = oH0[r];
      pO[sub][qloc][32 + l31] = oH1[r];
    }
    if (hi == 0) {
      pM[sub][l31] = mmH;
      pL[sub][l31] = llH;
    }
  }

  __syncthreads();

  if (role == 0) {
    // merge head partial (LDS) into tail accumulator, write heavy rows
    const float m1 = pM[sub][l31];
    const float l1 = pL[sub][l31];
    const float mN = fmaxf(mmH, m1);
    const float a0 = exp2f(mmH - mN);
    const float a1 = exp2f(m1 - mN);
    const float li = 1.0f / (llH * a0 + l1 * a1);
#pragma unroll
    for (int r = 0; r < 16; r++) {
      const int qloc = (r & 3) + 8 * (r >> 2) + 4 * hi;
      float a0q = __shfl(a0, qloc);
      float a1q = __shfl(a1, qloc);
      float liq = __shfl(li, qloc);
      float v0 = oH0[r] * a0q + pO[sub][qloc][l31] * a1q;
      float v1 = oH1[r] * a0q + pO[sub][qloc][32 + l31] * a1q;
      u16* orow = out + (size_t)(b * SEQ + qH0 + qloc) * 1024 + h * 64 + l31;
      orow[0] = f2bf(v0 * liq);
      orow[32] = f2bf(v1 * liq);
    }
  }
}

extern "C" void kernel_launch(void* const* d_in, const int* in_sizes, int n_in,
                              void* d_out, int out_size, void* d_ws, size_t ws_size,
                              hipStream_t stream) {
  const float* x = (const float*)d_in[0];
  const float* w_norm1 = (const float*)d_in[1];
  const float* wq = (const float*)d_in[2];
  const float* wk = (const float*)d_in[3];
  const float* wv = (const float*)d_in[4];
  const float* wo = (const float*)d_in[5];
  const float* attn_scale = (const float*)d_in[6];
  const float* w_norm2 = (const float*)d_in[7];
  const float* wg = (const float*)d_in[8];
  const float* wu = (const float*)d_in[9];
  const float* wd = (const float*)d_in[10];
  const float* mlp_scale = (const float*)d_in[11];
  const float* cosb = (const float*)d_in[12];
  const float* sinb = (const float*)d_in[13];
  float* out = (float*)d_out;

  char* ws = (char*)d_ws;
  u16* wqkv_t = (u16*)(ws + 0);            // 1536x1024 bf16
  u16* wo_t = (u16*)(ws + 3145728);        // 1024x1024 bf16
  u16* wg_t = (u16*)(ws + 5242880);        // 4096x1024 bf16
  u16* wu_t = (u16*)(ws + 13631488);
  u16* wd_t = (u16*)(ws + 22020096);       // 1024x4096 bf16
  u16* xn = (u16*)(ws + 30408704);         // 4096x1024 bf16 (reused for xn2)
  float* qkv = (float*)(ws + 38797312);    // 4096x1536 f32
  u16* attn_o = (u16*)(ws + 38797312);     // alias (qkv dead)
  float* x1 = (float*)(ws + 47185920);     // 4096x1024 f32
  u16* q_rope = (u16*)(ws + 63963136);     // 2*16*2048*64 bf16
  u16* k_rope = (u16*)(ws + 72351744);     // 2*4*2048*64 bf16
  u16* vt = (u16*)(ws + 74448896);         // 2*4*64*2048 bf16
  u16* hbuf = (u16*)(ws + 63963136);       // alias (rope dead in FFN phase)

  dim3 tb(256);
  transpose_cast_kernel<<<dim3(32, 32), tb, 0, stream>>>(wq, wqkv_t, 1024, 1024);
  transpose_cast_kernel<<<dim3(8, 32), tb, 0, stream>>>(wk, wqkv_t + (size_t)1024 * 1024, 1024, 256);
  transpose_cast_kernel<<<dim3(8, 32), tb, 0, stream>>>(wv, wqkv_t + (size_t)1280 * 1024, 1024, 256);
  transpose_cast_kernel<<<dim3(32, 32), tb, 0, stream>>>(wo, wo_t, 1024, 1024);
  transpose_cast_kernel<<<dim3(128, 32), tb, 0, stream>>>(wg, wg_t, 1024, 4096);
  transpose_cast_kernel<<<dim3(128, 32), tb, 0, stream>>>(wu, wu_t, 1024, 4096);
  transpose_cast_kernel<<<dim3(32, 128), tb, 0, stream>>>(wd, wd_t, 4096, 1024);

  rmsnorm_kernel<<<4096, tb, 0, stream>>>(x, w_norm1, xn);
  gemmB<0><<<dim3(384), dim3(256), 0, stream>>>(xn, wqkv_t, 4096, 1536, 1024, qkv, nullptr, nullptr, nullptr);
  rope_kernel<<<10240, tb, 0, stream>>>(qkv, cosb, sinb, q_rope, k_rope);
  vtrans_kernel<<<2 * 4 * 32, tb, 0, stream>>>(qkv, vt);
  attn_kernel<<<256, dim3(512), 0, stream>>>(q_rope, k_rope, vt, attn_o);
  gemmB<1><<<dim3(256), dim3(256), 0, stream>>>(attn_o, wo_t, 4096, 1024, 1024, x1, x, attn_scale, nullptr);
  rmsnorm_kernel<<<4096, tb, 0, stream>>>(x1, w_norm2, xn);
  gemmA<2><<<dim3(256), dim3(512), 0, stream>>>(xn, wg_t, 4096, 4096, 1024, nullptr, nullptr, nullptr, hbuf);
  gemmA<3><<<dim3(256), dim3(512), 0, stream>>>(xn, wu_t, 4096, 4096, 1024, nullptr, nullptr, nullptr, hbuf);
  gemmB<1><<<dim3(256), dim3(256), 0, stream>>>(hbuf, wd_t, 4096, 1024, 4096, out, x1, mlp_scale, nullptr);
}

// Round 12
// 266.706 us; speedup vs baseline: 1.1391x; 1.0930x over previous
//
#include <hip/hip_runtime.h>
#include <hip/hip_bf16.h>
#include <cstdint>

typedef unsigned short u16;
typedef unsigned int u32;
typedef __attribute__((ext_vector_type(4))) float f32x4;
typedef __attribute__((ext_vector_type(8))) __bf16 bf16x8;

#define NH 16
#define NKV 4
#define SEQ 2048
#define NTOK 4096

__device__ inline u16 f2bf(float f) {
  return __builtin_bit_cast(u16, __float2bfloat16(f));
}
__device__ inline float bf2f(u16 u) {
  return __bfloat162float(__builtin_bit_cast(__hip_bfloat16, u));
}

#define GLDS(gp, lp) __builtin_amdgcn_global_load_lds( \
    (__attribute__((address_space(1))) void*)(gp), \
    (__attribute__((address_space(3))) void*)(lp), 16, 0, 0)

#define VMCNT0 asm volatile("s_waitcnt vmcnt(0)" ::: "memory")

// ---------------- RMSNorm (f32 in, bf16 out) ----------------
__global__ __launch_bounds__(256) void rmsnorm_kernel(
    const float* __restrict__ x, const float* __restrict__ w,
    u16* __restrict__ out) {
  int row = blockIdx.x;
  int tid = threadIdx.x;
  const float4 v = reinterpret_cast<const float4*>(x + (size_t)row * 1024)[tid];
  float ss = v.x * v.x + v.y * v.y + v.z * v.z + v.w * v.w;
#pragma unroll
  for (int off = 32; off; off >>= 1) ss += __shfl_xor(ss, off);
  __shared__ float red[4];
  int lane = tid & 63, wid = tid >> 6;
  if (lane == 0) red[wid] = ss;
  __syncthreads();
  float tot = red[0] + red[1] + red[2] + red[3];
  float r = rsqrtf(tot * (1.0f / 1024.0f) + 1e-6f);
  const float4 wv = reinterpret_cast<const float4*>(w)[tid];
  ushort4 o;
  o.x = f2bf(v.x * r * wv.x);
  o.y = f2bf(v.y * r * wv.y);
  o.z = f2bf(v.z * r * wv.z);
  o.w = f2bf(v.w * r * wv.w);
  reinterpret_cast<ushort4*>(out + (size_t)row * 1024)[tid] = o;
}

// ---------------- weight transpose + cast: src[K][N] f32 -> dst[N][K] bf16 ----------------
__global__ __launch_bounds__(256) void transpose_cast_kernel(
    const float* __restrict__ src, u16* __restrict__ dst, int K, int N) {
  __shared__ float tile[32][33];
  int n0 = blockIdx.x * 32, k0 = blockIdx.y * 32;
  int tx = threadIdx.x & 31, ty = threadIdx.x >> 5;  // ty: 0..7
#pragma unroll
  for (int i = 0; i < 4; i++)
    tile[ty + i * 8][tx] = src[(size_t)(k0 + ty + i * 8) * N + n0 + tx];
  __syncthreads();
#pragma unroll
  for (int i = 0; i < 4; i++)
    dst[(size_t)(n0 + ty + i * 8) * K + k0 + tx] = f2bf(tile[tx][ty + i * 8]);
}

// Shared epilogue
template <int EP>
__device__ inline void epi_store(float v, size_t idx, int col,
                                 float* __restrict__ outf,
                                 const float* __restrict__ res,
                                 const float* __restrict__ scale,
                                 u16* __restrict__ outb) {
  if (EP == 0) {
    outf[idx] = v;
  } else if (EP == 1) {
    outf[idx] = res[idx] + v * scale[col];
  } else if (EP == 2) {
    outb[idx] = f2bf(v / (1.0f + __expf(-v)));
  } else {
    outb[idx] = f2bf(bf2f(outb[idx]) * v);
  }
}

// ---------------- gemmB: 128x128 tile, BK=64, 4 waves ----------------
template <int EP>
__global__ __launch_bounds__(256, 1) void gemmB(
    const u16* __restrict__ A, const u16* __restrict__ Bt,
    int M, int N, int K,
    float* __restrict__ outf, const float* __restrict__ res,
    const float* __restrict__ scale, u16* __restrict__ outb) {
  __shared__ u16 SA[2][128 * 64];
  __shared__ u16 SB[2][128 * 64];
  const int tid = threadIdx.x, lane = tid & 63, w = tid >> 6;  // 0..3
  const int wr = w >> 1, wc = w & 1;
  const int lg = lane >> 4, lc = lane & 15, cx = lc & 7;

  const int r8 = blockIdx.x & 7, j = blockIdx.x >> 3;
  const int bm = ((r8 << 2) + (j & 3)) << 7;   // M=4096: 32 m-blocks, 4 per XCD
  const int bn = (j >> 2) << 7;

  const int swrow = lane >> 3;
  const int swcol = (lane & 7) ^ swrow;
  const u16* gA = A + (size_t)(bm + w * 32 + swrow) * K + swcol * 8;
  const u16* gB = Bt + (size_t)(bn + w * 32 + swrow) * K + swcol * 8;

  const int NT = K >> 6;
  f32x4 acc[4][4] = {};

#define SG2(T_) do { int sl_ = (T_) & 1; size_t ko_ = (size_t)(T_) * 64; \
    GLDS(gA + ko_,                   &SA[sl_][(w * 32) * 64]); \
    GLDS(gA + ko_ + (size_t)8 * K,   &SA[sl_][(w * 32 + 8) * 64]); \
    GLDS(gA + ko_ + (size_t)16 * K,  &SA[sl_][(w * 32 + 16) * 64]); \
    GLDS(gA + ko_ + (size_t)24 * K,  &SA[sl_][(w * 32 + 24) * 64]); \
    GLDS(gB + ko_,                   &SB[sl_][(w * 32) * 64]); \
    GLDS(gB + ko_ + (size_t)8 * K,   &SB[sl_][(w * 32 + 8) * 64]); \
    GLDS(gB + ko_ + (size_t)16 * K,  &SB[sl_][(w * 32 + 16) * 64]); \
    GLDS(gB + ko_ + (size_t)24 * K,  &SB[sl_][(w * 32 + 24) * 64]); } while (0)

  SG2(0);
  VMCNT0;
  __builtin_amdgcn_s_barrier();

  for (int t = 0; t < NT; ++t) {
    const u16* sa = &SA[t & 1][0];
    const u16* sb = &SB[t & 1][0];
    const bool more = (t + 1 < NT);

    bf16x8 bfr[4][2], afr[4][2];
#pragma unroll
    for (int n = 0; n < 4; n++) {
      const int row = wc * 64 + n * 16 + lc;
#pragma unroll
      for (int ks = 0; ks < 2; ks++)
        bfr[n][ks] = *reinterpret_cast<const bf16x8*>(
            &sb[row * 64 + ((((ks << 2) | lg) ^ cx) << 3)]);
    }
#pragma unroll
    for (int i = 0; i < 4; i++) {
      const int row = wr * 64 + i * 16 + lc;
#pragma unroll
      for (int ks = 0; ks < 2; ks++)
        afr[i][ks] = *reinterpret_cast<const bf16x8*>(
            &sa[row * 64 + ((((ks << 2) | lg) ^ cx) << 3)]);
    }
    if (more) SG2(t + 1);
    __builtin_amdgcn_s_setprio(1);
#pragma unroll
    for (int i = 0; i < 4; i++)
#pragma unroll
      for (int n = 0; n < 4; n++) {
        acc[i][n] = __builtin_amdgcn_mfma_f32_16x16x32_bf16(afr[i][0], bfr[n][0], acc[i][n], 0, 0, 0);
        acc[i][n] = __builtin_amdgcn_mfma_f32_16x16x32_bf16(afr[i][1], bfr[n][1], acc[i][n], 0, 0, 0);
      }
    __builtin_amdgcn_s_setprio(0);
    VMCNT0;
    __builtin_amdgcn_s_barrier();
  }
#undef SG2

#pragma unroll
  for (int mi = 0; mi < 4; mi++)
#pragma unroll
    for (int ni = 0; ni < 4; ni++)
#pragma unroll
      for (int rg = 0; rg < 4; rg++) {
        const int row = bm + wr * 64 + mi * 16 + lg * 4 + rg;
        const int col = bn + wc * 64 + ni * 16 + lc;
        epi_store<EP>(acc[mi][ni][rg], (size_t)row * N + col, col, outf, res, scale, outb);
      }
}

// ---------------- fused gate+up GEMM: h = silu(xn@wg) * (xn@wu), bf16 out ----------------
// 256x128 tile, BK=32, 8 waves (4x2), A shared between both products. LDS 64KB.
__global__ __launch_bounds__(512, 2) void gateup_kernel(
    const u16* __restrict__ A, const u16* __restrict__ Bg,
    const u16* __restrict__ Bu, u16* __restrict__ outb) {
  const int K = 1024, N = 4096;
  __shared__ u16 SA[2][256 * 32];
  __shared__ u16 SG[2][128 * 32];
  __shared__ u16 SU[2][128 * 32];
  const int tid = threadIdx.x, lane = tid & 63, w = tid >> 6;  // 8 waves
  const int wr = w >> 1, wc = w & 1;
  const int lg = lane >> 4, lc = lane & 15;

  // bijective XCD map: 512 blocks = 16 m-blocks x 32 n-blocks
  const int r8 = blockIdx.x & 7, j = blockIdx.x >> 3;  // j: 0..63
  const int bm = (((r8 >> 1) << 2) + (j & 3)) << 8;
  const int bn = ((r8 & 1) * 16 + (j >> 2)) << 7;

  // staging: row = tid>>2 (0..127), chunk = tid&3 (16B); source pre-swizzled by row&3
  const int srow = tid >> 2;
  const int scs = ((tid & 3) ^ (srow & 3)) * 8;  // u16
  const u16* gAs = A + (size_t)(bm + srow) * K + scs;
  const u16* gGs = Bg + (size_t)(bn + srow) * K + scs;
  const u16* gUs = Bu + (size_t)(bn + srow) * K + scs;

  f32x4 accG[4][4] = {}, accU[4][4] = {};

#define SGU(T_) do { int sl_ = (T_) & 1; size_t ko_ = (size_t)(T_) * 32; \
    GLDS(gAs + ko_,                   &SA[sl_][w * 512]); \
    GLDS(gAs + ko_ + (size_t)128 * K, &SA[sl_][4096 + w * 512]); \
    GLDS(gGs + ko_,                   &SG[sl_][w * 512]); \
    GLDS(gUs + ko_,                   &SU[sl_][w * 512]); } while (0)

  SGU(0);
  VMCNT0;
  __builtin_amdgcn_s_barrier();

  for (int t = 0; t < 32; ++t) {
    const u16* sa = &SA[t & 1][0];
    const u16* sg = &SG[t & 1][0];
    const u16* su = &SU[t & 1][0];
    const bool more = (t + 1 < 32);

    bf16x8 afr[4], gfr[4], ufr[4];
#pragma unroll
    for (int i = 0; i < 4; i++) {
      const int row = wr * 64 + i * 16 + lc;
      afr[i] = *reinterpret_cast<const bf16x8*>(
          &sa[row * 32 + ((lg ^ (lc & 3)) << 3)]);
    }
#pragma unroll
    for (int n = 0; n < 4; n++) {
      const int row = wc * 64 + n * 16 + lc;
      const int off = row * 32 + ((lg ^ (lc & 3)) << 3);
      gfr[n] = *reinterpret_cast<const bf16x8*>(&sg[off]);
      ufr[n] = *reinterpret_cast<const bf16x8*>(&su[off]);
    }
    if (more) SGU(t + 1);
    __builtin_amdgcn_s_setprio(1);
#pragma unroll
    for (int i = 0; i < 4; i++)
#pragma unroll
      for (int n = 0; n < 4; n++) {
        accG[i][n] = __builtin_amdgcn_mfma_f32_16x16x32_bf16(afr[i], gfr[n], accG[i][n], 0, 0, 0);
        accU[i][n] = __builtin_amdgcn_mfma_f32_16x16x32_bf16(afr[i], ufr[n], accU[i][n], 0, 0, 0);
      }
    __builtin_amdgcn_s_setprio(0);
    VMCNT0;
    __builtin_amdgcn_s_barrier();
  }
#undef SGU

#pragma unroll
  for (int mi = 0; mi < 4; mi++)
#pragma unroll
    for (int ni = 0; ni < 4; ni++)
#pragma unroll
      for (int rg = 0; rg < 4; rg++) {
        const int row = bm + wr * 64 + mi * 16 + lg * 4 + rg;
        const int col = bn + wc * 64 + ni * 16 + lc;
        const float g = accG[mi][ni][rg];
        const float u = accU[mi][ni][rg];
        outb[(size_t)row * N + col] = f2bf((g / (1.0f + __expf(-g))) * u);
      }
}

// ---------------- RoPE: qkv f32 -> q_rope (pre-scaled by 0.125*log2e) bf16, k_rope bf16 ----------------
__global__ __launch_bounds__(256) void rope_kernel(
    const float* __restrict__ qkv, const float* __restrict__ cosb,
    const float* __restrict__ sinb, u16* __restrict__ qr, u16* __restrict__ kr) {
  int idx = blockIdx.x * 256 + threadIdx.x;  // B*S*20*32 total
  int d = idx & 31;
  int t = idx >> 5;
  int head = t % 20;
  int bs = t / 20;  // 0..4095
  int s = bs & (SEQ - 1);
  int b = bs >> 11;
  const float* row = qkv + (size_t)bs * 1536;
  float c = cosb[s * 32 + d], sn = sinb[s * 32 + d];
  const float QSC = 0.18033688011112042f;  // 0.125 * log2(e)
  float x1, x2;
  if (head < 16) {
    x1 = row[head * 64 + d];
    x2 = row[head * 64 + d + 32];
    size_t o = ((size_t)(b * NH + head) * SEQ + s) * 64 + d;
    qr[o] = f2bf((x1 * c + x2 * sn) * QSC);
    qr[o + 32] = f2bf((x2 * c - x1 * sn) * QSC);
  } else {
    int kh = head - 16;
    x1 = row[1024 + kh * 64 + d];
    x2 = row[1024 + kh * 64 + d + 32];
    size_t o = ((size_t)(b * NKV + kh) * SEQ + s) * 64 + d;
    kr[o] = f2bf(x1 * c + x2 * sn);
    kr[o + 32] = f2bf(x2 * c - x1 * sn);
  }
}

// ---------------- V transpose: qkv f32 -> vt [b][kv][d][s] bf16 ----------------
__global__ __launch_bounds__(256) void vtrans_kernel(
    const float* __restrict__ qkv, u16* __restrict__ vt) {
  int blk = blockIdx.x;
  int st = blk & 31; blk >>= 5;
  int kvh = blk & 3; blk >>= 2;
  int b = blk;
  __shared__ u16 tile[64][65];
  int tx = threadIdx.x & 63;
  int ty = threadIdx.x >> 6;  // 0..3
  int s0 = st * 64;
#pragma unroll
  for (int i = 0; i < 16; i++) {
    int sl = i * 4 + ty;
    tile[sl][tx] = f2bf(qkv[(size_t)(b * SEQ + s0 + sl) * 1536 + 1280 + kvh * 64 + tx]);
  }
  __syncthreads();
  size_t vbase = (size_t)(b * NKV + kvh) * 64 * SEQ;
#pragma unroll
  for (int i = 0; i < 16; i++) {
    int dd = i * 4 + ty;
    vt[vbase + (size_t)dd * SEQ + s0 + tx] = tile[tx][dd];
  }
}

// ---------------- Flash attention v4 (best measured): 8 waves, folded strips {j, 15-j} ----------------
__global__ __launch_bounds__(512, 1) void attn_kernel(
    const u16* __restrict__ qr, const u16* __restrict__ kr,
    const u16* __restrict__ vt, u16* __restrict__ out) {
  __shared__ u16 Ks[2][64 * 64];   // [key][d], swizzled
  __shared__ u16 Vs[2][64 * 64];   // [d][key], swizzled
  __shared__ u16 Ps[8][32 * 64];   // per-wave P[q][key], swizzled

  const int n = blockIdx.x;                 // 256 blocks
  const int g = n & 7;                      // b*4+kvh
  const int b = g >> 2, kvh = g & 3;
  const int h = kvh * 4 + ((n >> 3) & 3);
  const int j = n >> 5;                     // 0..7

  const int tid = threadIdx.x;
  const int lane = tid & 63, w = tid >> 6;  // 8 waves
  const int lg = lane >> 4, lc = lane & 15;
  const int lc7 = lc & 7;

  const int isH = (w ^ (w >> 2)) & 1;       // SIMD w&3 gets one light + one heavy
  const int strip = isH ? (15 - j) : j;     // 128-row q strip
  const int q0w = strip * 128 + (w >> 1) * 32;
  const int nt = 2 * (15 - j) + 2;          // tiles needed by heavy strip (18..32)

  bf16x8 qf[2][2];
  {
    const u16* qp = qr + ((size_t)(b * NH + h) * SEQ + q0w + lc) * 64 + lg * 8;
#pragma unroll
    for (int qt = 0; qt < 2; qt++) {
      qf[qt][0] = *reinterpret_cast<const bf16x8*>(qp + qt * 16 * 64);
      qf[qt][1] = *reinterpret_cast<const bf16x8*>(qp + qt * 16 * 64 + 32);
    }
  }
  VMCNT0;  // drain Q loads so in-loop vmcnt counting sees only GLDS

  const int srow = lane >> 3;                      // 0..7
  const int scw = ((lane & 7) ^ srow) << 3;        // pre-swizzled col (u16)
  const u16* ksrc = kr + (size_t)(b * NKV + kvh) * SEQ * 64 + (size_t)(w * 8 + srow) * 64 + scw;
  const u16* vsrc = vt + ((size_t)(b * NKV + kvh) * 64 + w * 8 + srow) * SEQ + scw;
  u16* Pw = &Ps[w][0];

#define STAGEA(bufi, t) do { \
    GLDS(ksrc + (size_t)(t) * 64 * 64, &Ks[bufi][(w * 8) * 64]); \
    GLDS(vsrc + (size_t)(t) * 64,      &Vs[bufi][(w * 8) * 64]); \
  } while (0)

  STAGEA(0, 0);

  float mm[2] = {-1e30f, -1e30f}, ll[2] = {0.0f, 0.0f};
  f32x4 oacc[2][4] = {};

  int buf = 0;
  for (int t = 0; t < nt; ++t) {
    if (t + 1 < nt) {
      STAGEA(buf ^ 1, t + 1);
      asm volatile("s_waitcnt vmcnt(2)" ::: "memory");
    } else {
      VMCNT0;
    }
    __builtin_amdgcn_s_barrier();
    __builtin_amdgcn_sched_barrier(0);

    const int c0 = t * 64;
    if (c0 <= q0w + 31) {
      bf16x8 kf[4][2];
#pragma unroll
      for (int ni = 0; ni < 4; ni++) {
        const int row = ni * 16 + lc;
#pragma unroll
        for (int hf = 0; hf < 2; hf++)
          kf[ni][hf] = *reinterpret_cast<const bf16x8*>(
              &Ks[buf][row * 64 + ((((hf * 64 + lg * 16)) ^ (lc7 << 4)) >> 1)]);
      }
      f32x4 sc[4][2] = {};
      __builtin_amdgcn_s_setprio(1);
#pragma unroll
      for (int ni = 0; ni < 4; ni++)
#pragma unroll
        for (int qt = 0; qt < 2; qt++) {
          sc[ni][qt] = __builtin_amdgcn_mfma_f32_16x16x32_bf16(kf[ni][0], qf[qt][0], sc[ni][qt], 0, 0, 0);
          sc[ni][qt] = __builtin_amdgcn_mfma_f32_16x16x32_bf16(kf[ni][1], qf[qt][1], sc[ni][qt], 0, 0, 0);
        }
      __builtin_amdgcn_s_setprio(0);
      bf16x8 vf[4][2];
#pragma unroll
      for (int dt = 0; dt < 4; dt++) {
        const int row = dt * 16 + lc;
#pragma unroll
        for (int ks = 0; ks < 2; ks++)
          vf[dt][ks] = *reinterpret_cast<const bf16x8*>(
              &Vs[buf][row * 64 + (((ks * 64 + lg * 16) ^ (lc7 << 4)) >> 1)]);
      }
      if (c0 + 63 > q0w) {
#pragma unroll
        for (int qt = 0; qt < 2; qt++) {
          const int q = q0w + qt * 16 + lc;
#pragma unroll
          for (int ni = 0; ni < 4; ni++)
#pragma unroll
            for (int rg = 0; rg < 4; rg++)
              if (c0 + ni * 16 + lg * 4 + rg > q) sc[ni][qt][rg] = -1e30f;
        }
      }
      float mx[2];
#pragma unroll
      for (int qt = 0; qt < 2; qt++) {
        float v = -1e30f;
#pragma unroll
        for (int ni = 0; ni < 4; ni++)
#pragma unroll
          for (int rg = 0; rg < 4; rg++) v = fmaxf(v, sc[ni][qt][rg]);
        v = fmaxf(v, __shfl_xor(v, 16));
        v = fmaxf(v, __shfl_xor(v, 32));
        mx[qt] = v;
      }
      if (!__all(mx[0] - mm[0] <= 11.5f && mx[1] - mm[1] <= 11.5f)) {
        float al[2];
#pragma unroll
        for (int qt = 0; qt < 2; qt++) {
          float mn = fmaxf(mm[qt], mx[qt]);
          al[qt] = exp2f(mm[qt] - mn);
          mm[qt] = mn;
          ll[qt] *= al[qt];
        }
#pragma unroll
        for (int qt = 0; qt < 2; qt++)
#pragma unroll
          for (int rg = 0; rg < 4; rg++) {
            float a = __shfl(al[qt], lg * 4 + rg);
#pragma unroll
            for (int dt = 0; dt < 4; dt++) oacc[qt][dt][rg] *= a;
          }
      }
#pragma unroll
      for (int qt = 0; qt < 2; qt++) {
        float rs = 0.0f;
#pragma unroll
        for (int ni = 0; ni < 4; ni++)
#pragma unroll
          for (int rg = 0; rg < 4; rg++) {
            float p = exp2f(sc[ni][qt][rg] - mm[qt]);
            sc[ni][qt][rg] = p;
            rs += p;
          }
        rs += __shfl_xor(rs, 16);
        rs += __shfl_xor(rs, 32);
        ll[qt] += rs;
      }
#pragma unroll
      for (int qt = 0; qt < 2; qt++)
#pragma unroll
        for (int ni = 0; ni < 4; ni++) {
          ushort4 pk;
          pk.x = f2bf(sc[ni][qt][0]);
          pk.y = f2bf(sc[ni][qt][1]);
          pk.z = f2bf(sc[ni][qt][2]);
          pk.w = f2bf(sc[ni][qt][3]);
          *reinterpret_cast<ushort4*>(
              &Pw[(qt * 16 + lc) * 64 + (((ni * 32 + lg * 8) ^ (lc7 << 4)) >> 1)]) = pk;
        }
      __builtin_amdgcn_s_setprio(1);
#pragma unroll
      for (int qt = 0; qt < 2; qt++)
#pragma unroll
        for (int ks = 0; ks < 2; ks++) {
          bf16x8 pa = *reinterpret_cast<const bf16x8*>(
              &Pw[(qt * 16 + lc) * 64 + (((ks * 64 + lg * 16) ^ (lc7 << 4)) >> 1)]);
#pragma unroll
          for (int dt = 0; dt < 4; dt++)
            oacc[qt][dt] = __builtin_amdgcn_mfma_f32_16x16x32_bf16(pa, vf[dt][ks], oacc[qt][dt], 0, 0, 0);
        }
      __builtin_amdgcn_s_setprio(0);
    }
    asm volatile("s_waitcnt lgkmcnt(0)" ::: "memory");
    __builtin_amdgcn_s_barrier();
    __builtin_amdgcn_sched_barrier(0);
    buf ^= 1;
  }
#undef STAGEA

#pragma unroll
  for (int qt = 0; qt < 2; qt++) {
    const float li = 1.0f / ll[qt];
#pragma unroll
    for (int rg = 0; rg < 4; rg++) {
      float liq = __shfl(li, lg * 4 + rg);
      int q = q0w + qt * 16 + lg * 4 + rg;
      u16* orow = out + (size_t)(b * SEQ + q) * 1024 + h * 64 + lc;
#pragma unroll
      for (int dt = 0; dt < 4; dt++)
        orow[dt * 16] = f2bf(oacc[qt][dt][rg] * liq);
    }
  }
}

extern "C" void kernel_launch(void* const* d_in, const int* in_sizes, int n_in,
                              void* d_out, int out_size, void* d_ws, size_t ws_size,
                              hipStream_t stream) {
  const float* x = (const float*)d_in[0];
  const float* w_norm1 = (const float*)d_in[1];
  const float* wq = (const float*)d_in[2];
  const float* wk = (const float*)d_in[3];
  const float* wv = (const float*)d_in[4];
  const float* wo = (const float*)d_in[5];
  const float* attn_scale = (const float*)d_in[6];
  const float* w_norm2 = (const float*)d_in[7];
  const float* wg = (const float*)d_in[8];
  const float* wu = (const float*)d_in[9];
  const float* wd = (const float*)d_in[10];
  const float* mlp_scale = (const float*)d_in[11];
  const float* cosb = (const float*)d_in[12];
  const float* sinb = (const float*)d_in[13];
  float* out = (float*)d_out;

  char* ws = (char*)d_ws;
  u16* wqkv_t = (u16*)(ws + 0);            // 1536x1024 bf16
  u16* wo_t = (u16*)(ws + 3145728);        // 1024x1024 bf16
  u16* wg_t = (u16*)(ws + 5242880);        // 4096x1024 bf16
  u16* wu_t = (u16*)(ws + 13631488);
  u16* wd_t = (u16*)(ws + 22020096);       // 1024x4096 bf16
  u16* xn = (u16*)(ws + 30408704);         // 4096x1024 bf16 (reused for xn2)
  float* qkv = (float*)(ws + 38797312);    // 4096x1536 f32
  u16* attn_o = (u16*)(ws + 38797312);     // alias (qkv dead)
  float* x1 = (float*)(ws + 47185920);     // 4096x1024 f32
  u16* q_rope = (u16*)(ws + 63963136);     // 2*16*2048*64 bf16
  u16* k_rope = (u16*)(ws + 72351744);     // 2*4*2048*64 bf16
  u16* vt = (u16*)(ws + 74448896);         // 2*4*64*2048 bf16
  u16* hbuf = (u16*)(ws + 63963136);       // alias (rope dead in FFN phase)

  dim3 tb(256);
  transpose_cast_kernel<<<dim3(32, 32), tb, 0, stream>>>(wq, wqkv_t, 1024, 1024);
  transpose_cast_kernel<<<dim3(8, 32), tb, 0, stream>>>(wk, wqkv_t + (size_t)1024 * 1024, 1024, 256);
  transpose_cast_kernel<<<dim3(8, 32), tb, 0, stream>>>(wv, wqkv_t + (size_t)1280 * 1024, 1024, 256);
  transpose_cast_kernel<<<dim3(32, 32), tb, 0, stream>>>(wo, wo_t, 1024, 1024);
  transpose_cast_kernel<<<dim3(128, 32), tb, 0, stream>>>(wg, wg_t, 1024, 4096);
  transpose_cast_kernel<<<dim3(128, 32), tb, 0, stream>>>(wu, wu_t, 1024, 4096);
  transpose_cast_kernel<<<dim3(32, 128), tb, 0, stream>>>(wd, wd_t, 4096, 1024);

  rmsnorm_kernel<<<4096, tb, 0, stream>>>(x, w_norm1, xn);
  gemmB<0><<<dim3(384), dim3(256), 0, stream>>>(xn, wqkv_t, 4096, 1536, 1024, qkv, nullptr, nullptr, nullptr);
  rope_kernel<<<10240, tb, 0, stream>>>(qkv, cosb, sinb, q_rope, k_rope);
  vtrans_kernel<<<2 * 4 * 32, tb, 0, stream>>>(qkv, vt);
  attn_kernel<<<256, dim3(512), 0, stream>>>(q_rope, k_rope, vt, attn_o);
  gemmB<1><<<dim3(256), dim3(256), 0, stream>>>(attn_o, wo_t, 4096, 1024, 1024, x1, x, attn_scale, nullptr);
  rmsnorm_kernel<<<4096, tb, 0, stream>>>(x1, w_norm2, xn);
  gateup_kernel<<<dim3(512), dim3(512), 0, stream>>>(xn, wg_t, wu_t, hbuf);
  gemmB<1><<<dim3(256), dim3(256), 0, stream>>>(hbuf, wd_t, 4096, 1024, 4096, out, x1, mlp_scale, nullptr);
}